// Round 1
// baseline (67581.573 us; speedup 1.0000x reference)
//
#include <hip/hip_runtime.h>
#include <math.h>

// FWMemory: T=1024 sequential ticks, persistent-kernel design.
// Phases per tick: A(gates matvec + LSTM) -> B(write/read/hWout dots) ->
// C(memory dual-matvec + ||M||^2) -> D(WG0: scalars, LN, out, err) -> A...
// 4 sync boundaries/step via agent-scope atomics; all WGs co-resident (256 WGs, 1/CU).

#define TT 1024
#define DD 2048
#define SS 1024
#define OO 512
#define MM 48
#define MSQ 2304
#define NG 4096
#define NWG 256
#define NTHR 256
#define NDOTS 753   // 241 head dots + 512 hWout dots

// ---- ws layout (4-byte word offsets) ----
#define W_BARA  0           // [1024] int, one-shot barrier counters
#define W_BARB  1024        // [1024]
#define W_ARRC  2048        // [1024]
#define W_FLG   3072        // [1024]
#define W_GARR  4096        // [64] per-column-group arrive counters (monotonic)
#define W_HB    4352        // [2][1024] h double buffer
#define W_CV    6400        // [1024] c (WG-local)
#define W_ERR   7424        // [512]
#define W_WR    7936        // [256] raw write(145)+read(96) dots
#define W_HWO   8192        // [512] h @ W_out
#define W_VOLDP 8704        // [48*4] per-chunk partials of M@key
#define W_NRAWP 8896        // [48*4] per-chunk partials of M@rk
#define W_M2P   9088        // [160] per-unit partials of sum(M^2)
#define W_UD    9248        // [64]  beta*invg*delta[a]
#define W_INVG  9312        // [16]
#define W_KEYF  9328        // [2304] materialized key vector
#define W_MEM   11632       // [48*2304] fast-weight memory
#define W_PART  122224      // [3][4096] gate partials from quarters 1..3
#define ZERO_WORDS 134512
#define W_PRE   134656              // [1024*4096] precomputed gates
#define W_WWRT  (W_PRE + TT*NG)     // [241*1024] W_write|W_read transposed
#define W_WOUTT (W_WWRT + 241*SS)   // [512*1024] W_out transposed
#define W_WCOMB (W_WOUTT + OO*SS)   // [48*512]  W_rproj @ W_out
#define W_BCOMB (W_WCOMB + MM*OO)   // [512]     b_rproj @ W_out + b_out
#define WS_WORDS (W_BCOMB + OO)

__device__ __forceinline__ float ld_g(const float* p) {
  return __hip_atomic_load(p, __ATOMIC_RELAXED, __HIP_MEMORY_SCOPE_AGENT);
}
__device__ __forceinline__ void st_g(float* p, float v) {
  __hip_atomic_store(p, v, __ATOMIC_RELAXED, __HIP_MEMORY_SCOPE_AGENT);
}
__device__ __forceinline__ int ld_i(const int* p) {
  return __hip_atomic_load(p, __ATOMIC_RELAXED, __HIP_MEMORY_SCOPE_AGENT);
}
__device__ __forceinline__ float sigm(float x) { return 1.f / (1.f + expf(-x)); }

// Full grid barrier on a one-shot counter (never reused across steps).
__device__ __forceinline__ void fullbar(int* c) {
  __syncthreads();  // drains each thread's vmcnt -> scoped stores are at MALL
  if (threadIdx.x == 0) {
    __hip_atomic_fetch_add(c, 1, __ATOMIC_RELEASE, __HIP_MEMORY_SCOPE_AGENT);
    while (ld_i(c) < NWG) __builtin_amdgcn_s_sleep(1);
    (void)__hip_atomic_load(c, __ATOMIC_ACQUIRE, __HIP_MEMORY_SCOPE_AGENT);
  }
  __syncthreads();
}

// ---------------- one-time prep kernels ----------------

__global__ void build_wwrT(const float* __restrict__ Ww, const float* __restrict__ Wr,
                           float* __restrict__ wwrT) {
  int id = blockIdx.x * 256 + threadIdx.x;
  if (id < 241 * SS) {
    int d = id >> 10, s = id & 1023;
    wwrT[id] = (d < 145) ? Ww[s * 145 + d] : Wr[s * 96 + (d - 145)];
  }
}

__global__ void build_woutT(const float* __restrict__ Wo, float* __restrict__ woutT) {
  int id = blockIdx.x * 256 + threadIdx.x;  // 512*1024 exact
  int o = id >> 10, s = id & 1023;
  woutT[id] = Wo[s * OO + o];
}

__global__ void wcomb_kernel(const float* __restrict__ Wrp, const float* __restrict__ brp,
                             const float* __restrict__ Wo, const float* __restrict__ bo,
                             float* __restrict__ wcomb, float* __restrict__ bcomb) {
  int id = blockIdx.x * 256 + threadIdx.x;  // 49*512 exact
  int a = id >> 9, o = id & 511;
  if (a < MM) {
    float acc = 0.f;
    for (int s = 0; s < SS; ++s) acc = fmaf(Wrp[a * SS + s], Wo[s * OO + o], acc);
    wcomb[a * OO + o] = acc;
  } else if (a == MM) {
    float acc = bo[o];
    for (int s = 0; s < SS; ++s) acc = fmaf(brp[s], Wo[s * OO + o], acc);
    bcomb[o] = acc;
  }
}

// pregates[t][j] = b_lstm[j] + inp[t] @ Wl[0:2048] + labels[t-1] @ Wl[2560:3072]
__global__ __launch_bounds__(256)
void pregate_gemm(const float* __restrict__ inp, const float* __restrict__ lab,
                  const float* __restrict__ Wl, const float* __restrict__ bl,
                  float* __restrict__ pre) {
  __shared__ float As[16][65];
  __shared__ float Bs[16][64];
  const int tid = threadIdx.x;
  const int j0 = blockIdx.x * 64;
  const int t0 = blockIdx.y * 64;
  const int tx = tid & 15, ty = tid >> 4;
  float acc[4][4] = {};
  for (int kc = 0; kc < 2560; kc += 16) {
    __syncthreads();
#pragma unroll
    for (int p = 0; p < 4; ++p) {
      int id = tid + p * 256;
      int r = id >> 4, kk = id & 15;
      int t = t0 + r, k = kc + kk;
      float v;
      if (k < DD) v = inp[(size_t)t * DD + k];
      else v = (t > 0) ? lab[(size_t)(t - 1) * OO + (k - DD)] : 0.f;
      As[kk][r] = v;
      int kr = id >> 6, j = id & 63;
      int k2 = kc + kr;
      int wrow = (k2 < DD) ? k2 : (512 + k2);  // 2560+(k2-2048)
      Bs[kr][j] = Wl[(size_t)wrow * NG + j0 + j];
    }
    __syncthreads();
#pragma unroll
    for (int kk = 0; kk < 16; ++kk) {
      float av[4], bv[4];
#pragma unroll
      for (int i = 0; i < 4; ++i) av[i] = As[kk][ty * 4 + i];
#pragma unroll
      for (int i = 0; i < 4; ++i) bv[i] = Bs[kk][tx * 4 + i];
#pragma unroll
      for (int i = 0; i < 4; ++i)
#pragma unroll
        for (int jx = 0; jx < 4; ++jx) acc[i][jx] = fmaf(av[i], bv[jx], acc[i][jx]);
    }
  }
#pragma unroll
  for (int i = 0; i < 4; ++i) {
    int t = t0 + ty * 4 + i;
#pragma unroll
    for (int jx = 0; jx < 4; ++jx) {
      int j = j0 + tx * 4 + jx;
      pre[(size_t)t * NG + j] = acc[i][jx] + bl[j];
    }
  }
}

// ---------------- persistent scan kernel ----------------

__global__ __launch_bounds__(NTHR, 1)
void persistent_kernel(float* ws, const float* __restrict__ Wl,
                       const float* __restrict__ labels,
                       const float* __restrict__ bwv, const float* __restrict__ brv,
                       float* __restrict__ out) {
  float* const hbuf = ws + W_HB;
  float* const cv = ws + W_CV;
  float* const errv = ws + W_ERR;
  float* const wrv = ws + W_WR;
  float* const hwo = ws + W_HWO;
  float* const voldp = ws + W_VOLDP;
  float* const nrawp = ws + W_NRAWP;
  float* const m2p = ws + W_M2P;
  float* const udv = ws + W_UD;
  float* const invg = ws + W_INVG;
  float* const keyf = ws + W_KEYF;
  float* const Mmem = ws + W_MEM;
  float* const part = ws + W_PART;
  const float* const pre = ws + W_PRE;
  const float* const wwrT = ws + W_WWRT;
  const float* const woutT = ws + W_WOUTT;
  const float* const wcomb = ws + W_WCOMB;
  const float* const bcomb = ws + W_BCOMB;
  int* const barA = (int*)(ws + W_BARA);
  int* const barB = (int*)(ws + W_BARB);
  int* const arrC = (int*)(ws + W_ARRC);
  int* const flg = (int*)(ws + W_FLG);
  int* const garr = (int*)(ws + W_GARR);

  const int w = blockIdx.x;
  const int tid = threadIdx.x;
  const int q = w >> 6;  // quarter (row split of the 1536 sequential rows)
  const int g = w & 63;  // column group (16 s-values per group)

  __shared__ float xs[384];
  __shared__ float pg[64];
  __shared__ float red[4][16][17];
  __shared__ float gsum[64];
  __shared__ float hlds[SS];
  __shared__ float t1[96], t2[96], s3[MM];
  __shared__ float lvold[MM], lnraw[MM], nvln_s[MM];
  __shared__ float dsc[8];
  __shared__ float wred[4];
  __shared__ float cred[3][4];

  for (int t = 0; t < TT; ++t) {
    // ---- wait for D(t-1), then phase A ----
    if (t > 0) {
      if (tid == 0) {
        const int* f = flg + (t - 1);
        while (ld_i(f) == 0) __builtin_amdgcn_s_sleep(1);
        (void)__hip_atomic_load(f, __ATOMIC_ACQUIRE, __HIP_MEMORY_SCOPE_AGENT);
      }
      __syncthreads();
      // memory rank-1 update for step t-1 (same WG that reads this slice in C)
      if (w < 144) {
        int a = w / 3, ch = w % 3;
        float uda = ld_g(udv + a);
        float ivg = ld_g(invg);
        float* Mrow = Mmem + a * MSQ + ch * 768;
#pragma unroll
        for (int i = 0; i < 3; ++i) {
          int c = tid + i * 256;
          float kvv = ld_g(keyf + ch * 768 + c);
          Mrow[c] = Mrow[c] * ivg + uda * kvv;  // plain: WG-local data
        }
      }
    }
    // stage x = [err(512); h_prev(1024)] slice for this quarter
    {
      const float* hprev = hbuf + (((t & 1) ^ 1) * SS);
      for (int l = tid; l < 384; l += NTHR) {
        int ri = q * 384 + l;
        xs[l] = (ri < 512) ? ld_g(errv + ri) : ld_g(hprev + (ri - 512));
      }
      if (tid < 64)
        pg[tid] = pre[(size_t)t * NG + (tid >> 4) * 1024 + g * 16 + (tid & 15)];
    }
    __syncthreads();
    // matvec: this quarter's 384 rows x this group's 16 columns x 4 gate blocks
    {
      int rl = tid >> 4, jj = tid & 15;
      int colb = g * 16 + jj;
      float a0 = 0.f, a1 = 0.f, a2 = 0.f, a3 = 0.f;
#pragma unroll 4
      for (int it = 0; it < 24; ++it) {
        int l = rl + 16 * it;
        int ri = q * 384 + l;
        int wrow = (ri < 512) ? (2048 + ri) : (2560 + ri);
        const float* Wp = Wl + (size_t)wrow * NG + colb;
        float xv = xs[l];
        a0 = fmaf(xv, Wp[0], a0);
        a1 = fmaf(xv, Wp[1024], a1);
        a2 = fmaf(xv, Wp[2048], a2);
        a3 = fmaf(xv, Wp[3072], a3);
      }
      red[0][rl][jj] = a0; red[1][rl][jj] = a1;
      red[2][rl][jj] = a2; red[3][rl][jj] = a3;
    }
    __syncthreads();
    float psum = 0.f;
    if (tid < 64) {
      int gb = tid >> 4, jj2 = tid & 15;
#pragma unroll
      for (int rl = 0; rl < 16; ++rl) psum += red[gb][rl][jj2];
    }
    if (q != 0) {
      if (tid < 64) {
        int gb = tid >> 4, jj2 = tid & 15;
        st_g(part + (q - 1) * NG + gb * 1024 + g * 16 + jj2, psum);
      }
      __syncthreads();
      if (tid == 0)
        __hip_atomic_fetch_add(garr + g, 1, __ATOMIC_RELEASE, __HIP_MEMORY_SCOPE_AGENT);
    } else {
      // designated updater: wait for the other 3 quarters, finish gates + LSTM cell
      if (tid == 0) {
        int tgt = 3 * (t + 1);
        while (ld_i(garr + g) < tgt) __builtin_amdgcn_s_sleep(1);
        (void)__hip_atomic_load(garr + g, __ATOMIC_ACQUIRE, __HIP_MEMORY_SCOPE_AGENT);
      }
      __syncthreads();
      if (tid < 64) {
        int gb = tid >> 4, jj2 = tid & 15;
        float v = psum + pg[tid];
        v += ld_g(part + 0 * NG + gb * 1024 + g * 16 + jj2);
        v += ld_g(part + 1 * NG + gb * 1024 + g * 16 + jj2);
        v += ld_g(part + 2 * NG + gb * 1024 + g * 16 + jj2);
        gsum[tid] = v;
      }
      __syncthreads();
      if (tid < 16) {
        int s = g * 16 + tid;
        float gi = gsum[0 * 16 + tid], gg = gsum[1 * 16 + tid];
        float gf = gsum[2 * 16 + tid], go = gsum[3 * 16 + tid];
        float cn = sigm(gf + 1.f) * cv[s] + sigm(gi) * tanhf(gg);
        float hn = sigm(go) * tanhf(cn);
        cv[s] = cn;  // plain: always this WG
        st_g(hbuf + (t & 1) * SS + s, hn);
      }
    }
    fullbar(barA + t);

    // ---- phase B: 753 dots of h (write 145, read 96, h@W_out 512) ----
    {
      const float* hcur = hbuf + (t & 1) * SS;
      for (int l = tid; l < SS; l += NTHR) hlds[l] = ld_g(hcur + l);
    }
    __syncthreads();
    for (int d = w; d < NDOTS; d += NWG) {
      const float* wrow = (d < 241) ? (wwrT + (size_t)d * SS)
                                    : (woutT + (size_t)(d - 241) * SS);
      float acc = 0.f;
#pragma unroll
      for (int i = 0; i < 4; ++i)
        acc = fmaf(hlds[tid + i * 256], wrow[tid + i * 256], acc);
#pragma unroll
      for (int off = 32; off; off >>= 1) acc += __shfl_down(acc, off, 64);
      if ((tid & 63) == 0) wred[tid >> 6] = acc;
      __syncthreads();
      if (tid == 0) {
        float v = wred[0] + wred[1] + wred[2] + wred[3];
        if (d < 145) st_g(wrv + d, v + bwv[d]);
        else if (d < 241) st_g(wrv + d, v + brv[d - 145]);
        else st_g(hwo + (d - 241), v);
      }
      __syncthreads();
    }
    fullbar(barB + t);

    // ---- phase C: dual matvec over M + sum(M^2), per (row, chunk) unit ----
    if (w < 144) {
      int a = w / 3, ch = w % 3;
      if (tid < 96) t1[tid] = tanhf(ld_g(wrv + tid));                    // k1|k2
      else if (tid < 192) t2[tid - 96] = tanhf(ld_g(wrv + 145 + (tid - 96)));  // n|e
      __syncthreads();
      const float* Mrow = Mmem + a * MSQ + ch * 768;
      float sk = 0.f, sr = 0.f, s2 = 0.f;
#pragma unroll
      for (int i = 0; i < 3; ++i) {
        int c = tid + i * 256;
        int gc = ch * 768 + c;
        int a2 = gc / 48, b2 = gc - a2 * 48;
        float m = Mrow[c];
        sk = fmaf(m, t1[a2] * t1[48 + b2], sk);
        sr = fmaf(m, t2[a2] * t2[48 + b2], sr);
        s2 = fmaf(m, m, s2);
      }
#pragma unroll
      for (int off = 32; off; off >>= 1) {
        sk += __shfl_down(sk, off, 64);
        sr += __shfl_down(sr, off, 64);
        s2 += __shfl_down(s2, off, 64);
      }
      if ((tid & 63) == 0) {
        cred[0][tid >> 6] = sk; cred[1][tid >> 6] = sr; cred[2][tid >> 6] = s2;
      }
      __syncthreads();
      if (tid == 0) {
        st_g(voldp + a * 4 + ch, cred[0][0] + cred[0][1] + cred[0][2] + cred[0][3]);
        st_g(nrawp + a * 4 + ch, cred[1][0] + cred[1][1] + cred[1][2] + cred[1][3]);
        st_g(m2p + w, cred[2][0] + cred[2][1] + cred[2][2] + cred[2][3]);
      }
    }
    __syncthreads();
    if (tid == 0)
      __hip_atomic_fetch_add(arrC + t, 1, __ATOMIC_RELEASE, __HIP_MEMORY_SCOPE_AGENT);

    // ---- phase D (WG0 only): scalars, LN, output, error, update coeffs ----
    if (w == 0) {
      if (tid == 0) {
        while (ld_i(arrC + t) < NWG) __builtin_amdgcn_s_sleep(1);
        (void)__hip_atomic_load(arrC + t, __ATOMIC_ACQUIRE, __HIP_MEMORY_SCOPE_AGENT);
      }
      __syncthreads();
      if (tid < 96) t1[tid] = tanhf(ld_g(wrv + tid));
      else if (tid < 192) t2[tid - 96] = tanhf(ld_g(wrv + 145 + (tid - 96)));
      else if (tid < 240) s3[tid - 192] = tanhf(ld_g(wrv + 96 + (tid - 192)));  // v
      __syncthreads();
      if (tid < MM) {
        lvold[tid] = ld_g(voldp + tid * 4) + ld_g(voldp + tid * 4 + 1) + ld_g(voldp + tid * 4 + 2);
        lnraw[tid] = ld_g(nrawp + tid * 4) + ld_g(nrawp + tid * 4 + 1) + ld_g(nrawp + tid * 4 + 2);
      }
      __syncthreads();
      if (tid == 0) {
        float m2 = 0.f;
        for (int i = 0; i < 144; ++i) m2 += ld_g(m2p + i);
        float beta = sigm(ld_g(wrv + 144));
        float sdv = 0.f, sdd = 0.f, sk1 = 0.f, sk2 = 0.f, skn = 0.f, ske = 0.f;
        for (int a = 0; a < MM; ++a) {
          float d = s3[a] - lvold[a];
          sdv += d * lvold[a];
          sdd += d * d;
          sk1 += t1[a] * t1[a];
          sk2 += t1[48 + a] * t1[48 + a];
          skn += t1[a] * t2[a];
          ske += t1[48 + a] * t2[48 + a];
        }
        float n2 = m2 + 2.f * beta * sdv + beta * beta * sdd * (sk1 * sk2);
        float gam = sqrtf(fmaxf(n2, 0.f));
        if (gam < 1.f) gam = 1.f;
        float ivg = 1.f / gam;
        float kdr = skn * ske;  // key . read_key
        float mean = 0.f, msq = 0.f;
        for (int a = 0; a < MM; ++a) {
          float d = s3[a] - lvold[a];
          float nv = (lnraw[a] + beta * d * kdr) * ivg;
          nvln_s[a] = nv;
          mean += nv;
          msq += nv * nv;
        }
        mean *= (1.f / 48.f);
        msq *= (1.f / 48.f);
        float rstd = rsqrtf(msq - mean * mean + 1e-5f);
        dsc[0] = mean; dsc[1] = rstd; dsc[2] = beta; dsc[3] = ivg;
        st_g(invg, ivg);
      }
      __syncthreads();
      if (tid < MM) {
        nvln_s[tid] = (nvln_s[tid] - dsc[0]) * dsc[1];
        st_g(udv + tid, dsc[2] * dsc[3] * (s3[tid] - lvold[tid]));
      }
      for (int i = tid; i < MSQ; i += NTHR) {
        int a2 = i / 48, b2 = i - a2 * 48;
        st_g(keyf + i, t1[a2] * t1[48 + b2]);
      }
      __syncthreads();
      for (int o = tid; o < OO; o += NTHR) {
        float acc = ld_g(hwo + o) + bcomb[o];
#pragma unroll 8
        for (int a = 0; a < MM; ++a) acc = fmaf(nvln_s[a], wcomb[a * OO + o], acc);
        float y = 10.f * tanhf(acc * 0.1f);
        out[(size_t)t * OO + o] = y;
        st_g(errv + o, y - labels[(size_t)t * OO + o]);
      }
      __syncthreads();
      if (tid == 0)
        __hip_atomic_store(flg + t, 1, __ATOMIC_RELEASE, __HIP_MEMORY_SCOPE_AGENT);
    }
  }
}

extern "C" void kernel_launch(void* const* d_in, const int* in_sizes, int n_in,
                              void* d_out, int out_size, void* d_ws, size_t ws_size,
                              hipStream_t stream) {
  const float* inp = (const float*)d_in[0];
  const float* lab = (const float*)d_in[1];
  const float* Wl = (const float*)d_in[2];
  const float* bl = (const float*)d_in[3];
  const float* Ww = (const float*)d_in[4];
  const float* bw = (const float*)d_in[5];
  const float* Wr = (const float*)d_in[6];
  const float* br = (const float*)d_in[7];
  const float* Wrp = (const float*)d_in[8];
  const float* brp = (const float*)d_in[9];
  const float* Wo = (const float*)d_in[10];
  const float* bo = (const float*)d_in[11];
  float* ws = (float*)d_ws;
  float* outp = (float*)d_out;
  (void)in_sizes; (void)n_in; (void)out_size; (void)ws_size;

  hipMemsetAsync(d_ws, 0, (size_t)ZERO_WORDS * 4, stream);
  hipLaunchKernelGGL(build_wwrT, dim3((241 * SS + 255) / 256), dim3(256), 0, stream,
                     Ww, Wr, ws + W_WWRT);
  hipLaunchKernelGGL(build_woutT, dim3(OO * SS / 256), dim3(256), 0, stream,
                     Wo, ws + W_WOUTT);
  hipLaunchKernelGGL(wcomb_kernel, dim3(98), dim3(256), 0, stream,
                     Wrp, brp, Wo, bo, ws + W_WCOMB, ws + W_BCOMB);
  hipLaunchKernelGGL(pregate_gemm, dim3(64, 16), dim3(256), 0, stream,
                     inp, lab, Wl, bl, ws + W_PRE);
  hipLaunchKernelGGL(persistent_kernel, dim3(NWG), dim3(NTHR), 0, stream,
                     ws, Wl, lab, bw, br, outp);
}

// Round 3
// 64712.860 us; speedup vs baseline: 1.0443x; 1.0443x over previous
//
#include <hip/hip_runtime.h>
#include <math.h>

// FWMemory: T=1024 sequential ticks, persistent-kernel design.
// Phases per tick: A(gates matvec + LSTM) -> B(write/read/hWout dots) ->
// C(memory dual-matvec + ||M||^2) -> D(WG0: scalars, LN, out, err) -> A...
// Sync via agent-scope atomics, NO acquire anywhere (agent acquire emits
// buffer_inv which nukes per-XCD L2 every step -> 28 GB re-fetch in R1).
// All cross-WG mutable data goes through sc1 relaxed atomics (served at
// MALL); producers use RELEASE (waitcnt) so data is at MALL before flags.
// Plain loads touch only read-only or WG-private data.
// R3 fix: restore the 4th wave partial in phase-C reduction (R2 typo).

#define TT 1024
#define DD 2048
#define SS 1024
#define OO 512
#define MM 48
#define MSQ 2304
#define NG 4096
#define NWG 256
#define NTHR 256
#define NDOTS 753   // 241 head dots + 512 hWout dots

// ---- ws layout (4-byte word offsets) ----
#define W_BARA  0           // [1024] int, one-shot barrier counters
#define W_BARB  1024        // [1024]
#define W_ARRC  2048        // [1024]
#define W_FLG   3072        // [1024]
#define W_GARR  4096        // [64] per-column-group arrive counters (monotonic)
#define W_HB    4352        // [2][1024] h double buffer
#define W_CV    6400        // [1024] c (WG-local)
#define W_ERR   7424        // [512]
#define W_WR    7936        // [256] raw write(145)+read(96) dots
#define W_HWO   8192        // [512] h @ W_out
#define W_VOLDP 8704        // [48*4] per-chunk partials of M@key
#define W_NRAWP 8896        // [48*4] per-chunk partials of M@rk
#define W_M2P   9088        // [160] per-unit partials of sum(M^2)
#define W_UD    9248        // [64]  beta*invg*delta[a]
#define W_INVG  9312        // [16]
#define W_KEYF  9328        // [2304] materialized key vector
#define W_MEM   11632       // [48*2304] fast-weight memory
#define W_PART  122224      // [3][4096] gate partials from quarters 1..3
#define ZERO_WORDS 134512
#define W_PRE   134656              // [1024*4096] precomputed gates
#define W_WWRT  (W_PRE + TT*NG)     // [241*1024] W_write|W_read transposed
#define W_WOUTT (W_WWRT + 241*SS)   // [512*1024] W_out transposed
#define W_WCOMB (W_WOUTT + OO*SS)   // [48*512]  W_rproj @ W_out
#define W_BCOMB (W_WCOMB + MM*OO)   // [512]     b_rproj @ W_out + b_out
#define WS_WORDS (W_BCOMB + OO)

__device__ __forceinline__ float ld_g(const float* p) {
  return __hip_atomic_load(p, __ATOMIC_RELAXED, __HIP_MEMORY_SCOPE_AGENT);
}
__device__ __forceinline__ void st_g(float* p, float v) {
  __hip_atomic_store(p, v, __ATOMIC_RELAXED, __HIP_MEMORY_SCOPE_AGENT);
}
__device__ __forceinline__ int ld_i(const int* p) {
  return __hip_atomic_load(p, __ATOMIC_RELAXED, __HIP_MEMORY_SCOPE_AGENT);
}
__device__ __forceinline__ float sigm(float x) { return 1.f / (1.f + expf(-x)); }

// Full grid barrier on a one-shot counter (never reused across steps).
__device__ __forceinline__ void fullbar(int* c) {
  __syncthreads();
  if (threadIdx.x == 0) {
    __hip_atomic_fetch_add(c, 1, __ATOMIC_RELEASE, __HIP_MEMORY_SCOPE_AGENT);
    while (ld_i(c) < NWG) __builtin_amdgcn_s_sleep(1);
  }
  __syncthreads();
}

// ---------------- one-time prep kernels ----------------

__global__ void build_wwrT(const float* __restrict__ Ww, const float* __restrict__ Wr,
                           float* __restrict__ wwrT) {
  int id = blockIdx.x * 256 + threadIdx.x;
  if (id < 241 * SS) {
    int d = id >> 10, s = id & 1023;
    wwrT[id] = (d < 145) ? Ww[s * 145 + d] : Wr[s * 96 + (d - 145)];
  }
}

__global__ void build_woutT(const float* __restrict__ Wo, float* __restrict__ woutT) {
  int id = blockIdx.x * 256 + threadIdx.x;  // 512*1024 exact
  int o = id >> 10, s = id & 1023;
  woutT[id] = Wo[s * OO + o];
}

__global__ void wcomb_kernel(const float* __restrict__ Wrp, const float* __restrict__ brp,
                             const float* __restrict__ Wo, const float* __restrict__ bo,
                             float* __restrict__ wcomb, float* __restrict__ bcomb) {
  int id = blockIdx.x * 256 + threadIdx.x;  // 49*512 exact
  int a = id >> 9, o = id & 511;
  if (a < MM) {
    float acc = 0.f;
    for (int s = 0; s < SS; ++s) acc = fmaf(Wrp[a * SS + s], Wo[s * OO + o], acc);
    wcomb[a * OO + o] = acc;
  } else if (a == MM) {
    float acc = bo[o];
    for (int s = 0; s < SS; ++s) acc = fmaf(brp[s], Wo[s * OO + o], acc);
    bcomb[o] = acc;
  }
}

// pregates[t][j] = b_lstm[j] + inp[t] @ Wl[0:2048] + labels[t-1] @ Wl[2560:3072]
__global__ __launch_bounds__(256)
void pregate_gemm(const float* __restrict__ inp, const float* __restrict__ lab,
                  const float* __restrict__ Wl, const float* __restrict__ bl,
                  float* __restrict__ pre) {
  __shared__ float As[16][65];
  __shared__ float Bs[16][64];
  const int tid = threadIdx.x;
  const int j0 = blockIdx.x * 64;
  const int t0 = blockIdx.y * 64;
  const int tx = tid & 15, ty = tid >> 4;
  float acc[4][4] = {};
  for (int kc = 0; kc < 2560; kc += 16) {
    __syncthreads();
#pragma unroll
    for (int p = 0; p < 4; ++p) {
      int id = tid + p * 256;
      int r = id >> 4, kk = id & 15;
      int t = t0 + r, k = kc + kk;
      float v;
      if (k < DD) v = inp[(size_t)t * DD + k];
      else v = (t > 0) ? lab[(size_t)(t - 1) * OO + (k - DD)] : 0.f;
      As[kk][r] = v;
      int kr = id >> 6, j = id & 63;
      int k2 = kc + kr;
      int wrow = (k2 < DD) ? k2 : (512 + k2);  // 2560+(k2-2048)
      Bs[kr][j] = Wl[(size_t)wrow * NG + j0 + j];
    }
    __syncthreads();
#pragma unroll
    for (int kk = 0; kk < 16; ++kk) {
      float av[4], bv[4];
#pragma unroll
      for (int i = 0; i < 4; ++i) av[i] = As[kk][ty * 4 + i];
#pragma unroll
      for (int i = 0; i < 4; ++i) bv[i] = Bs[kk][tx * 4 + i];
#pragma unroll
      for (int i = 0; i < 4; ++i)
#pragma unroll
        for (int jx = 0; jx < 4; ++jx) acc[i][jx] = fmaf(av[i], bv[jx], acc[i][jx]);
    }
  }
#pragma unroll
  for (int i = 0; i < 4; ++i) {
    int t = t0 + ty * 4 + i;
#pragma unroll
    for (int jx = 0; jx < 4; ++jx) {
      int j = j0 + tx * 4 + jx;
      pre[(size_t)t * NG + j] = acc[i][jx] + bl[j];
    }
  }
}

// ---------------- persistent scan kernel ----------------

__global__ __launch_bounds__(NTHR, 1)
void persistent_kernel(float* ws, const float* __restrict__ Wl,
                       const float* __restrict__ labels,
                       const float* __restrict__ bwv, const float* __restrict__ brv,
                       float* __restrict__ out) {
  float* const hbuf = ws + W_HB;
  float* const cv = ws + W_CV;
  float* const errv = ws + W_ERR;
  float* const wrv = ws + W_WR;
  float* const hwo = ws + W_HWO;
  float* const voldp = ws + W_VOLDP;
  float* const nrawp = ws + W_NRAWP;
  float* const m2p = ws + W_M2P;
  float* const udv = ws + W_UD;
  float* const invg = ws + W_INVG;
  float* const keyf = ws + W_KEYF;
  float* const Mmem = ws + W_MEM;
  float* const part = ws + W_PART;
  const float* const pre = ws + W_PRE;
  const float* const wwrT = ws + W_WWRT;
  const float* const woutT = ws + W_WOUTT;
  const float* const wcomb = ws + W_WCOMB;
  const float* const bcomb = ws + W_BCOMB;
  int* const barA = (int*)(ws + W_BARA);
  int* const barB = (int*)(ws + W_BARB);
  int* const arrC = (int*)(ws + W_ARRC);
  int* const flg = (int*)(ws + W_FLG);
  int* const garr = (int*)(ws + W_GARR);

  const int w = blockIdx.x;
  const int tid = threadIdx.x;
  const int q = w >> 6;  // quarter (row split of the 1536 sequential rows)
  const int g = w & 63;  // column group (16 s-values per group)

  __shared__ float xs[384];
  __shared__ float pg[64];
  __shared__ float red[4][16][17];
  __shared__ float gsum[64];
  __shared__ float hlds[SS];
  __shared__ float t1[96], t2[96], s3[MM];
  __shared__ float lvold[MM], lnraw[MM], nvln_s[MM];
  __shared__ float dsc[8];
  __shared__ float wred[4];
  __shared__ float cred[3][4];

  for (int t = 0; t < TT; ++t) {
    // ---- wait for D(t-1), then phase A ----
    if (t > 0) {
      if (tid == 0) {
        const int* f = flg + (t - 1);
        while (ld_i(f) == 0) __builtin_amdgcn_s_sleep(1);
      }
      __syncthreads();
      // memory rank-1 update for step t-1 (same WG that reads this slice in C)
      if (w < 144) {
        int a = w / 3, ch = w % 3;
        float uda = ld_g(udv + a);
        float ivg = ld_g(invg);
        float* Mrow = Mmem + a * MSQ + ch * 768;
#pragma unroll
        for (int i = 0; i < 3; ++i) {
          int c = tid + i * 256;
          float kvv = ld_g(keyf + ch * 768 + c);
          Mrow[c] = Mrow[c] * ivg + uda * kvv;  // plain: WG-local data
        }
      }
    }
    // stage x = [err(512); h_prev(1024)] slice for this quarter
    {
      const float* hprev = hbuf + (((t & 1) ^ 1) * SS);
      for (int l = tid; l < 384; l += NTHR) {
        int ri = q * 384 + l;
        xs[l] = (ri < 512) ? ld_g(errv + ri) : ld_g(hprev + (ri - 512));
      }
      if (tid < 64)
        pg[tid] = pre[(size_t)t * NG + (tid >> 4) * 1024 + g * 16 + (tid & 15)];
    }
    __syncthreads();
    // matvec: this quarter's 384 rows x this group's 16 columns x 4 gate blocks
    {
      int rl = tid >> 4, jj = tid & 15;
      int colb = g * 16 + jj;
      float a0 = 0.f, a1 = 0.f, a2 = 0.f, a3 = 0.f;
#pragma unroll 4
      for (int it = 0; it < 24; ++it) {
        int l = rl + 16 * it;
        int ri = q * 384 + l;
        int wrow = (ri < 512) ? (2048 + ri) : (2560 + ri);
        const float* Wp = Wl + (size_t)wrow * NG + colb;
        float xv = xs[l];
        a0 = fmaf(xv, Wp[0], a0);
        a1 = fmaf(xv, Wp[1024], a1);
        a2 = fmaf(xv, Wp[2048], a2);
        a3 = fmaf(xv, Wp[3072], a3);
      }
      red[0][rl][jj] = a0; red[1][rl][jj] = a1;
      red[2][rl][jj] = a2; red[3][rl][jj] = a3;
    }
    __syncthreads();
    float psum = 0.f;
    if (tid < 64) {
      int gb = tid >> 4, jj2 = tid & 15;
#pragma unroll
      for (int rl = 0; rl < 16; ++rl) psum += red[gb][rl][jj2];
    }
    if (q != 0) {
      if (tid < 64) {
        int gb = tid >> 4, jj2 = tid & 15;
        st_g(part + (q - 1) * NG + gb * 1024 + g * 16 + jj2, psum);
      }
      __syncthreads();
      if (tid == 0)
        __hip_atomic_fetch_add(garr + g, 1, __ATOMIC_RELEASE, __HIP_MEMORY_SCOPE_AGENT);
    } else {
      // designated updater: wait for the other 3 quarters, finish gates + LSTM cell
      if (tid == 0) {
        int tgt = 3 * (t + 1);
        while (ld_i(garr + g) < tgt) __builtin_amdgcn_s_sleep(1);
      }
      __syncthreads();
      if (tid < 64) {
        int gb = tid >> 4, jj2 = tid & 15;
        float v = psum + pg[tid];
        v += ld_g(part + 0 * NG + gb * 1024 + g * 16 + jj2);
        v += ld_g(part + 1 * NG + gb * 1024 + g * 16 + jj2);
        v += ld_g(part + 2 * NG + gb * 1024 + g * 16 + jj2);
        gsum[tid] = v;
      }
      __syncthreads();
      if (tid < 16) {
        int s = g * 16 + tid;
        float gi = gsum[0 * 16 + tid], gg = gsum[1 * 16 + tid];
        float gf = gsum[2 * 16 + tid], go = gsum[3 * 16 + tid];
        float cn = sigm(gf + 1.f) * cv[s] + sigm(gi) * tanhf(gg);
        float hn = sigm(go) * tanhf(cn);
        cv[s] = cn;  // plain: always this WG
        st_g(hbuf + (t & 1) * SS + s, hn);
      }
    }
    fullbar(barA + t);

    // ---- phase B: 753 dots of h (write 145, read 96, h@W_out 512) ----
    {
      const float* hcur = hbuf + (t & 1) * SS;
      for (int l = tid; l < SS; l += NTHR) hlds[l] = ld_g(hcur + l);
    }
    __syncthreads();
    for (int d = w; d < NDOTS; d += NWG) {
      const float* wrow = (d < 241) ? (wwrT + (size_t)d * SS)
                                    : (woutT + (size_t)(d - 241) * SS);
      float acc = 0.f;
#pragma unroll
      for (int i = 0; i < 4; ++i)
        acc = fmaf(hlds[tid + i * 256], wrow[tid + i * 256], acc);
#pragma unroll
      for (int off = 32; off; off >>= 1) acc += __shfl_down(acc, off, 64);
      if ((tid & 63) == 0) wred[tid >> 6] = acc;
      __syncthreads();
      if (tid == 0) {
        float v = wred[0] + wred[1] + wred[2] + wred[3];
        if (d < 145) st_g(wrv + d, v + bwv[d]);
        else if (d < 241) st_g(wrv + d, v + brv[d - 145]);
        else st_g(hwo + (d - 241), v);
      }
      __syncthreads();
    }
    fullbar(barB + t);

    // ---- phase C: dual matvec over M + sum(M^2), per (row, chunk) unit ----
    if (w < 144) {
      int a = w / 3, ch = w % 3;
      if (tid < 96) t1[tid] = tanhf(ld_g(wrv + tid));                    // k1|k2
      else if (tid < 192) t2[tid - 96] = tanhf(ld_g(wrv + 145 + (tid - 96)));  // n|e
      __syncthreads();
      const float* Mrow = Mmem + a * MSQ + ch * 768;
      float sk = 0.f, sr = 0.f, s2 = 0.f;
#pragma unroll
      for (int i = 0; i < 3; ++i) {
        int c = tid + i * 256;
        int gc = ch * 768 + c;
        int a2 = gc / 48, b2 = gc - a2 * 48;
        float m = Mrow[c];
        sk = fmaf(m, t1[a2] * t1[48 + b2], sk);
        sr = fmaf(m, t2[a2] * t2[48 + b2], sr);
        s2 = fmaf(m, m, s2);
      }
#pragma unroll
      for (int off = 32; off; off >>= 1) {
        sk += __shfl_down(sk, off, 64);
        sr += __shfl_down(sr, off, 64);
        s2 += __shfl_down(s2, off, 64);
      }
      if ((tid & 63) == 0) {
        cred[0][tid >> 6] = sk; cred[1][tid >> 6] = sr; cred[2][tid >> 6] = s2;
      }
      __syncthreads();
      if (tid == 0) {
        st_g(voldp + a * 4 + ch, cred[0][0] + cred[0][1] + cred[0][2] + cred[0][3]);
        st_g(nrawp + a * 4 + ch, cred[1][0] + cred[1][1] + cred[1][2] + cred[1][3]);
        st_g(m2p + w, cred[2][0] + cred[2][1] + cred[2][2] + cred[2][3]);
      }
    }
    __syncthreads();
    if (tid == 0)
      __hip_atomic_fetch_add(arrC + t, 1, __ATOMIC_RELEASE, __HIP_MEMORY_SCOPE_AGENT);

    // ---- phase D (WG0 only): scalars, LN, output, error, update coeffs ----
    if (w == 0) {
      if (tid == 0) {
        while (ld_i(arrC + t) < NWG) __builtin_amdgcn_s_sleep(1);
      }
      __syncthreads();
      if (tid < 96) t1[tid] = tanhf(ld_g(wrv + tid));
      else if (tid < 192) t2[tid - 96] = tanhf(ld_g(wrv + 145 + (tid - 96)));
      else if (tid < 240) s3[tid - 192] = tanhf(ld_g(wrv + 96 + (tid - 192)));  // v
      __syncthreads();
      if (tid < MM) {
        lvold[tid] = ld_g(voldp + tid * 4) + ld_g(voldp + tid * 4 + 1) + ld_g(voldp + tid * 4 + 2);
        lnraw[tid] = ld_g(nrawp + tid * 4) + ld_g(nrawp + tid * 4 + 1) + ld_g(nrawp + tid * 4 + 2);
      }
      __syncthreads();
      if (tid == 0) {
        float m2 = 0.f;
        for (int i = 0; i < 144; ++i) m2 += ld_g(m2p + i);
        float beta = sigm(ld_g(wrv + 144));
        float sdv = 0.f, sdd = 0.f, sk1 = 0.f, sk2 = 0.f, skn = 0.f, ske = 0.f;
        for (int a = 0; a < MM; ++a) {
          float d = s3[a] - lvold[a];
          sdv += d * lvold[a];
          sdd += d * d;
          sk1 += t1[a] * t1[a];
          sk2 += t1[48 + a] * t1[48 + a];
          skn += t1[a] * t2[a];
          ske += t1[48 + a] * t2[48 + a];
        }
        float n2 = m2 + 2.f * beta * sdv + beta * beta * sdd * (sk1 * sk2);
        float gam = sqrtf(fmaxf(n2, 0.f));
        if (gam < 1.f) gam = 1.f;
        float ivg = 1.f / gam;
        float kdr = skn * ske;  // key . read_key
        float mean = 0.f, msq = 0.f;
        for (int a = 0; a < MM; ++a) {
          float d = s3[a] - lvold[a];
          float nv = (lnraw[a] + beta * d * kdr) * ivg;
          nvln_s[a] = nv;
          mean += nv;
          msq += nv * nv;
        }
        mean *= (1.f / 48.f);
        msq *= (1.f / 48.f);
        float rstd = rsqrtf(msq - mean * mean + 1e-5f);
        dsc[0] = mean; dsc[1] = rstd; dsc[2] = beta; dsc[3] = ivg;
        st_g(invg, ivg);
      }
      __syncthreads();
      if (tid < MM) {
        nvln_s[tid] = (nvln_s[tid] - dsc[0]) * dsc[1];
        st_g(udv + tid, dsc[2] * dsc[3] * (s3[tid] - lvold[tid]));
      }
      for (int i = tid; i < MSQ; i += NTHR) {
        int a2 = i / 48, b2 = i - a2 * 48;
        st_g(keyf + i, t1[a2] * t1[48 + b2]);
      }
      __syncthreads();
      for (int o = tid; o < OO; o += NTHR) {
        float acc = ld_g(hwo + o) + bcomb[o];
#pragma unroll 8
        for (int a = 0; a < MM; ++a) acc = fmaf(nvln_s[a], wcomb[a * OO + o], acc);
        float y = 10.f * tanhf(acc * 0.1f);
        out[(size_t)t * OO + o] = y;
        st_g(errv + o, y - labels[(size_t)t * OO + o]);
      }
      __syncthreads();
      if (tid == 0)
        __hip_atomic_store(flg + t, 1, __ATOMIC_RELEASE, __HIP_MEMORY_SCOPE_AGENT);
    }
  }
}

extern "C" void kernel_launch(void* const* d_in, const int* in_sizes, int n_in,
                              void* d_out, int out_size, void* d_ws, size_t ws_size,
                              hipStream_t stream) {
  const float* inp = (const float*)d_in[0];
  const float* lab = (const float*)d_in[1];
  const float* Wl = (const float*)d_in[2];
  const float* bl = (const float*)d_in[3];
  const float* Ww = (const float*)d_in[4];
  const float* bw = (const float*)d_in[5];
  const float* Wr = (const float*)d_in[6];
  const float* br = (const float*)d_in[7];
  const float* Wrp = (const float*)d_in[8];
  const float* brp = (const float*)d_in[9];
  const float* Wo = (const float*)d_in[10];
  const float* bo = (const float*)d_in[11];
  float* ws = (float*)d_ws;
  float* outp = (float*)d_out;
  (void)in_sizes; (void)n_in; (void)out_size; (void)ws_size;

  hipMemsetAsync(d_ws, 0, (size_t)ZERO_WORDS * 4, stream);
  hipLaunchKernelGGL(build_wwrT, dim3((241 * SS + 255) / 256), dim3(256), 0, stream,
                     Ww, Wr, ws + W_WWRT);
  hipLaunchKernelGGL(build_woutT, dim3(OO * SS / 256), dim3(256), 0, stream,
                     Wo, ws + W_WOUTT);
  hipLaunchKernelGGL(wcomb_kernel, dim3(98), dim3(256), 0, stream,
                     Wrp, brp, Wo, bo, ws + W_WCOMB, ws + W_BCOMB);
  hipLaunchKernelGGL(pregate_gemm, dim3(64, 16), dim3(256), 0, stream,
                     inp, lab, Wl, bl, ws + W_PRE);
  hipLaunchKernelGGL(persistent_kernel, dim3(NWG), dim3(NTHR), 0, stream,
                     ws, Wl, lab, bw, br, outp);
}

// Round 4
// 53261.780 us; speedup vs baseline: 1.2689x; 1.2150x over previous
//
#include <hip/hip_runtime.h>
#include <math.h>

// FWMemory: T=1024 sequential ticks, persistent-kernel design.
// Phases per tick: A(gates matvec + LSTM) -> B(write/read/hWout dots) ->
// C(memory dual-matvec + ||M||^2) -> D(WG0: scalars, LN, out, err) -> A...
// Sync via agent-scope relaxed sc1 atomics (no acquire anywhere).
// R4 change: phase-A weights repacked into per-WG contiguous 96KB blocks
// ([wg][row384][col16][gate4], float4 loads). R3 showed the 16KB-row-stride
// column slices fold into ~24 lines/set (>16-way L2) -> cyclic LRU thrash ->
// 25MB refetch/step. Contiguous per-WG blocks spread over all sets -> L2-resident.

#define TT 1024
#define DD 2048
#define SS 1024
#define OO 512
#define MM 48
#define MSQ 2304
#define NG 4096
#define NWG 256
#define NTHR 256
#define NDOTS 753   // 241 head dots + 512 hWout dots

// ---- ws layout (4-byte word offsets) ----
#define W_BARA  0           // [1024] int, one-shot barrier counters
#define W_BARB  1024        // [1024]
#define W_ARRC  2048        // [1024]
#define W_FLG   3072        // [1024]
#define W_GARR  4096        // [64] per-column-group arrive counters (monotonic)
#define W_HB    4352        // [2][1024] h double buffer
#define W_CV    6400        // [1024] c (WG-local)
#define W_ERR   7424        // [512]
#define W_WR    7936        // [256] raw write(145)+read(96) dots
#define W_HWO   8192        // [512] h @ W_out
#define W_VOLDP 8704        // [48*4] per-chunk partials of M@key
#define W_NRAWP 8896        // [48*4] per-chunk partials of M@rk
#define W_M2P   9088        // [160] per-unit partials of sum(M^2)
#define W_UD    9248        // [64]  beta*invg*delta[a]
#define W_INVG  9312        // [16]
#define W_KEYF  9328        // [2304] materialized key vector
#define W_MEM   11632       // [48*2304] fast-weight memory
#define W_PART  122224      // [3][4096] gate partials from quarters 1..3
#define ZERO_WORDS 134512
#define W_PRE   134656              // [1024*4096] precomputed gates
#define W_WWRT  (W_PRE + TT*NG)     // [241*1024] W_write|W_read transposed
#define W_WOUTT (W_WWRT + 241*SS)   // [512*1024] W_out transposed
#define W_WCOMB (W_WOUTT + OO*SS)   // [48*512]  W_rproj @ W_out
#define W_BCOMB (W_WCOMB + MM*OO)   // [512]     b_rproj @ W_out + b_out
#define W_WLRP  (W_BCOMB + OO)      // [256*384*16*4] repacked seq rows of W_lstm
#define WS_WORDS (W_WLRP + 1536*NG)

__device__ __forceinline__ float ld_g(const float* p) {
  return __hip_atomic_load(p, __ATOMIC_RELAXED, __HIP_MEMORY_SCOPE_AGENT);
}
__device__ __forceinline__ void st_g(float* p, float v) {
  __hip_atomic_store(p, v, __ATOMIC_RELAXED, __HIP_MEMORY_SCOPE_AGENT);
}
__device__ __forceinline__ int ld_i(const int* p) {
  return __hip_atomic_load(p, __ATOMIC_RELAXED, __HIP_MEMORY_SCOPE_AGENT);
}
__device__ __forceinline__ float sigm(float x) { return 1.f / (1.f + expf(-x)); }

// Full grid barrier on a one-shot counter (never reused across steps).
__device__ __forceinline__ void fullbar(int* c) {
  __syncthreads();
  if (threadIdx.x == 0) {
    __hip_atomic_fetch_add(c, 1, __ATOMIC_RELEASE, __HIP_MEMORY_SCOPE_AGENT);
    while (ld_i(c) < NWG) __builtin_amdgcn_s_sleep(1);
  }
  __syncthreads();
}

// ---------------- one-time prep kernels ----------------

__global__ void build_wwrT(const float* __restrict__ Ww, const float* __restrict__ Wr,
                           float* __restrict__ wwrT) {
  int id = blockIdx.x * 256 + threadIdx.x;
  if (id < 241 * SS) {
    int d = id >> 10, s = id & 1023;
    wwrT[id] = (d < 145) ? Ww[s * 145 + d] : Wr[s * 96 + (d - 145)];
  }
}

__global__ void build_woutT(const float* __restrict__ Wo, float* __restrict__ woutT) {
  int id = blockIdx.x * 256 + threadIdx.x;  // 512*1024 exact
  int o = id >> 10, s = id & 1023;
  woutT[id] = Wo[s * OO + o];
}

// Repack W_lstm sequential rows into per-WG contiguous blocks:
// dst[(((w*384+row)*16+jj)*4)+gb] = Wl[wrow(q,row)*4096 + gb*1024 + g*16 + jj]
// where w=q*64+g. 1536*4096 elements exact.
__global__ void repack_wl(const float* __restrict__ Wl, float* __restrict__ dst) {
  int id = blockIdx.x * 256 + threadIdx.x;
  int gb = id & 3;
  int jj = (id >> 2) & 15;
  int tmp = id >> 6;
  int row = tmp % 384;
  int w = tmp / 384;
  int q = w >> 6, g = w & 63;
  int ri = q * 384 + row;
  int wrow = (ri < 512) ? (2048 + ri) : (2560 + ri);
  dst[id] = Wl[(size_t)wrow * NG + gb * 1024 + g * 16 + jj];
}

__global__ void wcomb_kernel(const float* __restrict__ Wrp, const float* __restrict__ brp,
                             const float* __restrict__ Wo, const float* __restrict__ bo,
                             float* __restrict__ wcomb, float* __restrict__ bcomb) {
  int id = blockIdx.x * 256 + threadIdx.x;  // 49*512 exact
  int a = id >> 9, o = id & 511;
  if (a < MM) {
    float acc = 0.f;
    for (int s = 0; s < SS; ++s) acc = fmaf(Wrp[a * SS + s], Wo[s * OO + o], acc);
    wcomb[a * OO + o] = acc;
  } else if (a == MM) {
    float acc = bo[o];
    for (int s = 0; s < SS; ++s) acc = fmaf(brp[s], Wo[s * OO + o], acc);
    bcomb[o] = acc;
  }
}

// pregates[t][j] = b_lstm[j] + inp[t] @ Wl[0:2048] + labels[t-1] @ Wl[2560:3072]
__global__ __launch_bounds__(256)
void pregate_gemm(const float* __restrict__ inp, const float* __restrict__ lab,
                  const float* __restrict__ Wl, const float* __restrict__ bl,
                  float* __restrict__ pre) {
  __shared__ float As[16][65];
  __shared__ float Bs[16][64];
  const int tid = threadIdx.x;
  const int j0 = blockIdx.x * 64;
  const int t0 = blockIdx.y * 64;
  const int tx = tid & 15, ty = tid >> 4;
  float acc[4][4] = {};
  for (int kc = 0; kc < 2560; kc += 16) {
    __syncthreads();
#pragma unroll
    for (int p = 0; p < 4; ++p) {
      int id = tid + p * 256;
      int r = id >> 4, kk = id & 15;
      int t = t0 + r, k = kc + kk;
      float v;
      if (k < DD) v = inp[(size_t)t * DD + k];
      else v = (t > 0) ? lab[(size_t)(t - 1) * OO + (k - DD)] : 0.f;
      As[kk][r] = v;
      int kr = id >> 6, j = id & 63;
      int k2 = kc + kr;
      int wrow = (k2 < DD) ? k2 : (512 + k2);  // 2560+(k2-2048)
      Bs[kr][j] = Wl[(size_t)wrow * NG + j0 + j];
    }
    __syncthreads();
#pragma unroll
    for (int kk = 0; kk < 16; ++kk) {
      float av[4], bv[4];
#pragma unroll
      for (int i = 0; i < 4; ++i) av[i] = As[kk][ty * 4 + i];
#pragma unroll
      for (int i = 0; i < 4; ++i) bv[i] = Bs[kk][tx * 4 + i];
#pragma unroll
      for (int i = 0; i < 4; ++i)
#pragma unroll
        for (int jx = 0; jx < 4; ++jx) acc[i][jx] = fmaf(av[i], bv[jx], acc[i][jx]);
    }
  }
#pragma unroll
  for (int i = 0; i < 4; ++i) {
    int t = t0 + ty * 4 + i;
#pragma unroll
    for (int jx = 0; jx < 4; ++jx) {
      int j = j0 + tx * 4 + jx;
      pre[(size_t)t * NG + j] = acc[i][jx] + bl[j];
    }
  }
}

// ---------------- persistent scan kernel ----------------

__global__ __launch_bounds__(NTHR, 1)
void persistent_kernel(float* ws, const float* __restrict__ labels,
                       const float* __restrict__ bwv, const float* __restrict__ brv,
                       float* __restrict__ out) {
  float* const hbuf = ws + W_HB;
  float* const cv = ws + W_CV;
  float* const errv = ws + W_ERR;
  float* const wrv = ws + W_WR;
  float* const hwo = ws + W_HWO;
  float* const voldp = ws + W_VOLDP;
  float* const nrawp = ws + W_NRAWP;
  float* const m2p = ws + W_M2P;
  float* const udv = ws + W_UD;
  float* const invg = ws + W_INVG;
  float* const keyf = ws + W_KEYF;
  float* const Mmem = ws + W_MEM;
  float* const part = ws + W_PART;
  const float* const pre = ws + W_PRE;
  const float* const wwrT = ws + W_WWRT;
  const float* const woutT = ws + W_WOUTT;
  const float* const wcomb = ws + W_WCOMB;
  const float* const bcomb = ws + W_BCOMB;
  int* const barA = (int*)(ws + W_BARA);
  int* const barB = (int*)(ws + W_BARB);
  int* const arrC = (int*)(ws + W_ARRC);
  int* const flg = (int*)(ws + W_FLG);
  int* const garr = (int*)(ws + W_GARR);

  const int w = blockIdx.x;
  const int tid = threadIdx.x;
  const int q = w >> 6;  // quarter (row split of the 1536 sequential rows)
  const int g = w & 63;  // column group (16 s-values per group)
  const float4* const blk4 =
      (const float4*)(ws + W_WLRP + (size_t)w * (384 * 16 * 4));

  __shared__ float xs[384];
  __shared__ float pg[64];
  __shared__ float red[4][16][17];
  __shared__ float gsum[64];
  __shared__ float hlds[SS];
  __shared__ float t1[96], t2[96], s3[MM];
  __shared__ float lvold[MM], lnraw[MM], nvln_s[MM];
  __shared__ float dsc[8];
  __shared__ float wred[4];
  __shared__ float cred[3][4];

  for (int t = 0; t < TT; ++t) {
    // ---- wait for D(t-1), then phase A ----
    if (t > 0) {
      if (tid == 0) {
        const int* f = flg + (t - 1);
        while (ld_i(f) == 0) __builtin_amdgcn_s_sleep(1);
      }
      __syncthreads();
      // memory rank-1 update for step t-1 (same WG that reads this slice in C)
      if (w < 144) {
        int a = w / 3, ch = w % 3;
        float uda = ld_g(udv + a);
        float ivg = ld_g(invg);
        float* Mrow = Mmem + a * MSQ + ch * 768;
#pragma unroll
        for (int i = 0; i < 3; ++i) {
          int c = tid + i * 256;
          float kvv = ld_g(keyf + ch * 768 + c);
          Mrow[c] = Mrow[c] * ivg + uda * kvv;  // plain: WG-local data
        }
      }
    }
    // stage x = [err(512); h_prev(1024)] slice for this quarter
    {
      const float* hprev = hbuf + (((t & 1) ^ 1) * SS);
      for (int l = tid; l < 384; l += NTHR) {
        int ri = q * 384 + l;
        xs[l] = (ri < 512) ? ld_g(errv + ri) : ld_g(hprev + (ri - 512));
      }
      if (tid < 64)
        pg[tid] = pre[(size_t)t * NG + (tid >> 4) * 1024 + g * 16 + (tid & 15)];
    }
    __syncthreads();
    // matvec: this quarter's 384 rows x this group's 16 columns x 4 gate blocks
    // repacked layout: blk4[row*16 + jj] = {gate0,gate1,gate2,gate3}
    {
      int rl = tid >> 4, jj = tid & 15;
      float a0 = 0.f, a1 = 0.f, a2 = 0.f, a3 = 0.f;
#pragma unroll 4
      for (int it = 0; it < 24; ++it) {
        int l = rl + 16 * it;
        float4 v = blk4[l * 16 + jj];
        float xv = xs[l];
        a0 = fmaf(xv, v.x, a0);
        a1 = fmaf(xv, v.y, a1);
        a2 = fmaf(xv, v.z, a2);
        a3 = fmaf(xv, v.w, a3);
      }
      red[0][rl][jj] = a0; red[1][rl][jj] = a1;
      red[2][rl][jj] = a2; red[3][rl][jj] = a3;
    }
    __syncthreads();
    float psum = 0.f;
    if (tid < 64) {
      int gb = tid >> 4, jj2 = tid & 15;
#pragma unroll
      for (int rl = 0; rl < 16; ++rl) psum += red[gb][rl][jj2];
    }
    if (q != 0) {
      if (tid < 64) {
        int gb = tid >> 4, jj2 = tid & 15;
        st_g(part + (q - 1) * NG + gb * 1024 + g * 16 + jj2, psum);
      }
      __syncthreads();
      if (tid == 0)
        __hip_atomic_fetch_add(garr + g, 1, __ATOMIC_RELEASE, __HIP_MEMORY_SCOPE_AGENT);
    } else {
      // designated updater: wait for the other 3 quarters, finish gates + LSTM cell
      if (tid == 0) {
        int tgt = 3 * (t + 1);
        while (ld_i(garr + g) < tgt) __builtin_amdgcn_s_sleep(1);
      }
      __syncthreads();
      if (tid < 64) {
        int gb = tid >> 4, jj2 = tid & 15;
        float v = psum + pg[tid];
        v += ld_g(part + 0 * NG + gb * 1024 + g * 16 + jj2);
        v += ld_g(part + 1 * NG + gb * 1024 + g * 16 + jj2);
        v += ld_g(part + 2 * NG + gb * 1024 + g * 16 + jj2);
        gsum[tid] = v;
      }
      __syncthreads();
      if (tid < 16) {
        int s = g * 16 + tid;
        float gi = gsum[0 * 16 + tid], gg = gsum[1 * 16 + tid];
        float gf = gsum[2 * 16 + tid], go = gsum[3 * 16 + tid];
        float cn = sigm(gf + 1.f) * cv[s] + sigm(gi) * tanhf(gg);
        float hn = sigm(go) * tanhf(cn);
        cv[s] = cn;  // plain: always this WG
        st_g(hbuf + (t & 1) * SS + s, hn);
      }
    }
    fullbar(barA + t);

    // ---- phase B: 753 dots of h (write 145, read 96, h@W_out 512) ----
    {
      const float* hcur = hbuf + (t & 1) * SS;
      for (int l = tid; l < SS; l += NTHR) hlds[l] = ld_g(hcur + l);
    }
    __syncthreads();
    for (int d = w; d < NDOTS; d += NWG) {
      const float* wrow = (d < 241) ? (wwrT + (size_t)d * SS)
                                    : (woutT + (size_t)(d - 241) * SS);
      float acc = 0.f;
#pragma unroll
      for (int i = 0; i < 4; ++i)
        acc = fmaf(hlds[tid + i * 256], wrow[tid + i * 256], acc);
#pragma unroll
      for (int off = 32; off; off >>= 1) acc += __shfl_down(acc, off, 64);
      if ((tid & 63) == 0) wred[tid >> 6] = acc;
      __syncthreads();
      if (tid == 0) {
        float v = wred[0] + wred[1] + wred[2] + wred[3];
        if (d < 145) st_g(wrv + d, v + bwv[d]);
        else if (d < 241) st_g(wrv + d, v + brv[d - 145]);
        else st_g(hwo + (d - 241), v);
      }
      __syncthreads();
    }
    fullbar(barB + t);

    // ---- phase C: dual matvec over M + sum(M^2), per (row, chunk) unit ----
    if (w < 144) {
      int a = w / 3, ch = w % 3;
      if (tid < 96) t1[tid] = tanhf(ld_g(wrv + tid));                    // k1|k2
      else if (tid < 192) t2[tid - 96] = tanhf(ld_g(wrv + 145 + (tid - 96)));  // n|e
      __syncthreads();
      const float* Mrow = Mmem + a * MSQ + ch * 768;
      float sk = 0.f, sr = 0.f, s2 = 0.f;
#pragma unroll
      for (int i = 0; i < 3; ++i) {
        int c = tid + i * 256;
        int gc = ch * 768 + c;
        int a2 = gc / 48, b2 = gc - a2 * 48;
        float m = Mrow[c];
        sk = fmaf(m, t1[a2] * t1[48 + b2], sk);
        sr = fmaf(m, t2[a2] * t2[48 + b2], sr);
        s2 = fmaf(m, m, s2);
      }
#pragma unroll
      for (int off = 32; off; off >>= 1) {
        sk += __shfl_down(sk, off, 64);
        sr += __shfl_down(sr, off, 64);
        s2 += __shfl_down(s2, off, 64);
      }
      if ((tid & 63) == 0) {
        cred[0][tid >> 6] = sk; cred[1][tid >> 6] = sr; cred[2][tid >> 6] = s2;
      }
      __syncthreads();
      if (tid == 0) {
        st_g(voldp + a * 4 + ch, cred[0][0] + cred[0][1] + cred[0][2] + cred[0][3]);
        st_g(nrawp + a * 4 + ch, cred[1][0] + cred[1][1] + cred[1][2] + cred[1][3]);
        st_g(m2p + w, cred[2][0] + cred[2][1] + cred[2][2] + cred[2][3]);
      }
    }
    __syncthreads();
    if (tid == 0)
      __hip_atomic_fetch_add(arrC + t, 1, __ATOMIC_RELEASE, __HIP_MEMORY_SCOPE_AGENT);

    // ---- phase D (WG0 only): scalars, LN, output, error, update coeffs ----
    if (w == 0) {
      if (tid == 0) {
        while (ld_i(arrC + t) < NWG) __builtin_amdgcn_s_sleep(1);
      }
      __syncthreads();
      if (tid < 96) t1[tid] = tanhf(ld_g(wrv + tid));
      else if (tid < 192) t2[tid - 96] = tanhf(ld_g(wrv + 145 + (tid - 96)));
      else if (tid < 240) s3[tid - 192] = tanhf(ld_g(wrv + 96 + (tid - 192)));  // v
      __syncthreads();
      if (tid < MM) {
        lvold[tid] = ld_g(voldp + tid * 4) + ld_g(voldp + tid * 4 + 1) + ld_g(voldp + tid * 4 + 2);
        lnraw[tid] = ld_g(nrawp + tid * 4) + ld_g(nrawp + tid * 4 + 1) + ld_g(nrawp + tid * 4 + 2);
      }
      __syncthreads();
      if (tid == 0) {
        float m2 = 0.f;
        for (int i = 0; i < 144; ++i) m2 += ld_g(m2p + i);
        float beta = sigm(ld_g(wrv + 144));
        float sdv = 0.f, sdd = 0.f, sk1 = 0.f, sk2 = 0.f, skn = 0.f, ske = 0.f;
        for (int a = 0; a < MM; ++a) {
          float d = s3[a] - lvold[a];
          sdv += d * lvold[a];
          sdd += d * d;
          sk1 += t1[a] * t1[a];
          sk2 += t1[48 + a] * t1[48 + a];
          skn += t1[a] * t2[a];
          ske += t1[48 + a] * t2[48 + a];
        }
        float n2 = m2 + 2.f * beta * sdv + beta * beta * sdd * (sk1 * sk2);
        float gam = sqrtf(fmaxf(n2, 0.f));
        if (gam < 1.f) gam = 1.f;
        float ivg = 1.f / gam;
        float kdr = skn * ske;  // key . read_key
        float mean = 0.f, msq = 0.f;
        for (int a = 0; a < MM; ++a) {
          float d = s3[a] - lvold[a];
          float nv = (lnraw[a] + beta * d * kdr) * ivg;
          nvln_s[a] = nv;
          mean += nv;
          msq += nv * nv;
        }
        mean *= (1.f / 48.f);
        msq *= (1.f / 48.f);
        float rstd = rsqrtf(msq - mean * mean + 1e-5f);
        dsc[0] = mean; dsc[1] = rstd; dsc[2] = beta; dsc[3] = ivg;
        st_g(invg, ivg);
      }
      __syncthreads();
      if (tid < MM) {
        nvln_s[tid] = (nvln_s[tid] - dsc[0]) * dsc[1];
        st_g(udv + tid, dsc[2] * dsc[3] * (s3[tid] - lvold[tid]));
      }
      for (int i = tid; i < MSQ; i += NTHR) {
        int a2 = i / 48, b2 = i - a2 * 48;
        st_g(keyf + i, t1[a2] * t1[48 + b2]);
      }
      __syncthreads();
      for (int o = tid; o < OO; o += NTHR) {
        float acc = ld_g(hwo + o) + bcomb[o];
#pragma unroll 8
        for (int a = 0; a < MM; ++a) acc = fmaf(nvln_s[a], wcomb[a * OO + o], acc);
        float y = 10.f * tanhf(acc * 0.1f);
        out[(size_t)t * OO + o] = y;
        st_g(errv + o, y - labels[(size_t)t * OO + o]);
      }
      __syncthreads();
      if (tid == 0)
        __hip_atomic_store(flg + t, 1, __ATOMIC_RELEASE, __HIP_MEMORY_SCOPE_AGENT);
    }
  }
}

extern "C" void kernel_launch(void* const* d_in, const int* in_sizes, int n_in,
                              void* d_out, int out_size, void* d_ws, size_t ws_size,
                              hipStream_t stream) {
  const float* inp = (const float*)d_in[0];
  const float* lab = (const float*)d_in[1];
  const float* Wl = (const float*)d_in[2];
  const float* bl = (const float*)d_in[3];
  const float* Ww = (const float*)d_in[4];
  const float* bw = (const float*)d_in[5];
  const float* Wr = (const float*)d_in[6];
  const float* br = (const float*)d_in[7];
  const float* Wrp = (const float*)d_in[8];
  const float* brp = (const float*)d_in[9];
  const float* Wo = (const float*)d_in[10];
  const float* bo = (const float*)d_in[11];
  float* ws = (float*)d_ws;
  float* outp = (float*)d_out;
  (void)in_sizes; (void)n_in; (void)out_size; (void)ws_size;

  hipMemsetAsync(d_ws, 0, (size_t)ZERO_WORDS * 4, stream);
  hipLaunchKernelGGL(build_wwrT, dim3((241 * SS + 255) / 256), dim3(256), 0, stream,
                     Ww, Wr, ws + W_WWRT);
  hipLaunchKernelGGL(build_woutT, dim3(OO * SS / 256), dim3(256), 0, stream,
                     Wo, ws + W_WOUTT);
  hipLaunchKernelGGL(repack_wl, dim3(1536 * NG / 256), dim3(256), 0, stream,
                     Wl, ws + W_WLRP);
  hipLaunchKernelGGL(wcomb_kernel, dim3(98), dim3(256), 0, stream,
                     Wrp, brp, Wo, bo, ws + W_WCOMB, ws + W_BCOMB);
  hipLaunchKernelGGL(pregate_gemm, dim3(64, 16), dim3(256), 0, stream,
                     inp, lab, Wl, bl, ws + W_PRE);
  hipLaunchKernelGGL(persistent_kernel, dim3(NWG), dim3(NTHR), 0, stream,
                     ws, lab, bw, br, outp);
}

// Round 5
// 51127.527 us; speedup vs baseline: 1.3218x; 1.0417x over previous
//
#include <hip/hip_runtime.h>
#include <math.h>

// FWMemory: T=1024 sequential ticks, persistent-kernel design.
// Phases per tick: A(gates matvec + LSTM) -> B(write/read/hWout dots) ->
// C(memory dual-matvec + ||M||^2) -> D(WG0: scalars, LN, out, err) -> A...
// Sync via agent-scope relaxed sc1 atomics (no acquire anywhere; R2/R3).
// R4: per-WG contiguous 96KB weight blocks -> L2-resident (FETCH 27MB->1.6MB/step).
// R5: phase D fully parallelized. The serial 144-iter MALL-latency loop
// (m2 sum, one lane, ~700cyc/iter ~= 42us/step) is replaced by parallel
// staging + wave-0 shuffle reduction; all 48-length scalar loops fold into
// lane-parallel wave-0 math. arrC target drops 256->144 (C WGs only).

#define TT 1024
#define DD 2048
#define SS 1024
#define OO 512
#define MM 48
#define MSQ 2304
#define NG 4096
#define NWG 256
#define NTHR 256
#define NDOTS 753   // 241 head dots + 512 hWout dots

// ---- ws layout (4-byte word offsets) ----
#define W_BARA  0           // [1024] int, one-shot barrier counters
#define W_BARB  1024        // [1024]
#define W_ARRC  2048        // [1024]
#define W_FLG   3072        // [1024]
#define W_GARR  4096        // [64] per-column-group arrive counters (monotonic)
#define W_HB    4352        // [2][1024] h double buffer
#define W_CV    6400        // [1024] c (WG-local)
#define W_ERR   7424        // [512]
#define W_WR    7936        // [256] raw write(145)+read(96) dots
#define W_HWO   8192        // [512] h @ W_out
#define W_VOLDP 8704        // [48*4] per-chunk partials of M@key
#define W_NRAWP 8896        // [48*4] per-chunk partials of M@rk
#define W_M2P   9088        // [160] per-unit partials of sum(M^2)
#define W_UD    9248        // [64]  beta*invg*delta[a]
#define W_INVG  9312        // [16]
#define W_KEYF  9328        // [2304] materialized key vector
#define W_MEM   11632       // [48*2304] fast-weight memory
#define W_PART  122224      // [3][4096] gate partials from quarters 1..3
#define ZERO_WORDS 134512
#define W_PRE   134656              // [1024*4096] precomputed gates
#define W_WWRT  (W_PRE + TT*NG)     // [241*1024] W_write|W_read transposed
#define W_WOUTT (W_WWRT + 241*SS)   // [512*1024] W_out transposed
#define W_WCOMB (W_WOUTT + OO*SS)   // [48*512]  W_rproj @ W_out
#define W_BCOMB (W_WCOMB + MM*OO)   // [512]     b_rproj @ W_out + b_out
#define W_WLRP  (W_BCOMB + OO)      // [256*384*16*4] repacked seq rows of W_lstm
#define WS_WORDS (W_WLRP + 1536*NG)

__device__ __forceinline__ float ld_g(const float* p) {
  return __hip_atomic_load(p, __ATOMIC_RELAXED, __HIP_MEMORY_SCOPE_AGENT);
}
__device__ __forceinline__ void st_g(float* p, float v) {
  __hip_atomic_store(p, v, __ATOMIC_RELAXED, __HIP_MEMORY_SCOPE_AGENT);
}
__device__ __forceinline__ int ld_i(const int* p) {
  return __hip_atomic_load(p, __ATOMIC_RELAXED, __HIP_MEMORY_SCOPE_AGENT);
}
__device__ __forceinline__ float sigm(float x) { return 1.f / (1.f + expf(-x)); }

// Full grid barrier on a one-shot counter (never reused across steps).
__device__ __forceinline__ void fullbar(int* c) {
  __syncthreads();
  if (threadIdx.x == 0) {
    __hip_atomic_fetch_add(c, 1, __ATOMIC_RELEASE, __HIP_MEMORY_SCOPE_AGENT);
    while (ld_i(c) < NWG) __builtin_amdgcn_s_sleep(1);
  }
  __syncthreads();
}

// ---------------- one-time prep kernels ----------------

__global__ void build_wwrT(const float* __restrict__ Ww, const float* __restrict__ Wr,
                           float* __restrict__ wwrT) {
  int id = blockIdx.x * 256 + threadIdx.x;
  if (id < 241 * SS) {
    int d = id >> 10, s = id & 1023;
    wwrT[id] = (d < 145) ? Ww[s * 145 + d] : Wr[s * 96 + (d - 145)];
  }
}

__global__ void build_woutT(const float* __restrict__ Wo, float* __restrict__ woutT) {
  int id = blockIdx.x * 256 + threadIdx.x;  // 512*1024 exact
  int o = id >> 10, s = id & 1023;
  woutT[id] = Wo[s * OO + o];
}

// Repack W_lstm sequential rows into per-WG contiguous blocks:
// dst[(((w*384+row)*16+jj)*4)+gb] = Wl[wrow(q,row)*4096 + gb*1024 + g*16 + jj]
__global__ void repack_wl(const float* __restrict__ Wl, float* __restrict__ dst) {
  int id = blockIdx.x * 256 + threadIdx.x;
  int gb = id & 3;
  int jj = (id >> 2) & 15;
  int tmp = id >> 6;
  int row = tmp % 384;
  int w = tmp / 384;
  int q = w >> 6, g = w & 63;
  int ri = q * 384 + row;
  int wrow = (ri < 512) ? (2048 + ri) : (2560 + ri);
  dst[id] = Wl[(size_t)wrow * NG + gb * 1024 + g * 16 + jj];
}

__global__ void wcomb_kernel(const float* __restrict__ Wrp, const float* __restrict__ brp,
                             const float* __restrict__ Wo, const float* __restrict__ bo,
                             float* __restrict__ wcomb, float* __restrict__ bcomb) {
  int id = blockIdx.x * 256 + threadIdx.x;  // 49*512 exact
  int a = id >> 9, o = id & 511;
  if (a < MM) {
    float acc = 0.f;
    for (int s = 0; s < SS; ++s) acc = fmaf(Wrp[a * SS + s], Wo[s * OO + o], acc);
    wcomb[a * OO + o] = acc;
  } else if (a == MM) {
    float acc = bo[o];
    for (int s = 0; s < SS; ++s) acc = fmaf(brp[s], Wo[s * OO + o], acc);
    bcomb[o] = acc;
  }
}

// pregates[t][j] = b_lstm[j] + inp[t] @ Wl[0:2048] + labels[t-1] @ Wl[2560:3072]
__global__ __launch_bounds__(256)
void pregate_gemm(const float* __restrict__ inp, const float* __restrict__ lab,
                  const float* __restrict__ Wl, const float* __restrict__ bl,
                  float* __restrict__ pre) {
  __shared__ float As[16][65];
  __shared__ float Bs[16][64];
  const int tid = threadIdx.x;
  const int j0 = blockIdx.x * 64;
  const int t0 = blockIdx.y * 64;
  const int tx = tid & 15, ty = tid >> 4;
  float acc[4][4] = {};
  for (int kc = 0; kc < 2560; kc += 16) {
    __syncthreads();
#pragma unroll
    for (int p = 0; p < 4; ++p) {
      int id = tid + p * 256;
      int r = id >> 4, kk = id & 15;
      int t = t0 + r, k = kc + kk;
      float v;
      if (k < DD) v = inp[(size_t)t * DD + k];
      else v = (t > 0) ? lab[(size_t)(t - 1) * OO + (k - DD)] : 0.f;
      As[kk][r] = v;
      int kr = id >> 6, j = id & 63;
      int k2 = kc + kr;
      int wrow = (k2 < DD) ? k2 : (512 + k2);  // 2560+(k2-2048)
      Bs[kr][j] = Wl[(size_t)wrow * NG + j0 + j];
    }
    __syncthreads();
#pragma unroll
    for (int kk = 0; kk < 16; ++kk) {
      float av[4], bv[4];
#pragma unroll
      for (int i = 0; i < 4; ++i) av[i] = As[kk][ty * 4 + i];
#pragma unroll
      for (int i = 0; i < 4; ++i) bv[i] = Bs[kk][tx * 4 + i];
#pragma unroll
      for (int i = 0; i < 4; ++i)
#pragma unroll
        for (int jx = 0; jx < 4; ++jx) acc[i][jx] = fmaf(av[i], bv[jx], acc[i][jx]);
    }
  }
#pragma unroll
  for (int i = 0; i < 4; ++i) {
    int t = t0 + ty * 4 + i;
#pragma unroll
    for (int jx = 0; jx < 4; ++jx) {
      int j = j0 + tx * 4 + jx;
      pre[(size_t)t * NG + j] = acc[i][jx] + bl[j];
    }
  }
}

// ---------------- persistent scan kernel ----------------

__global__ __launch_bounds__(NTHR, 1)
void persistent_kernel(float* ws, const float* __restrict__ labels,
                       const float* __restrict__ bwv, const float* __restrict__ brv,
                       float* __restrict__ out) {
  float* const hbuf = ws + W_HB;
  float* const cv = ws + W_CV;
  float* const errv = ws + W_ERR;
  float* const wrv = ws + W_WR;
  float* const hwo = ws + W_HWO;
  float* const voldp = ws + W_VOLDP;
  float* const nrawp = ws + W_NRAWP;
  float* const m2p = ws + W_M2P;
  float* const udv = ws + W_UD;
  float* const invg = ws + W_INVG;
  float* const keyf = ws + W_KEYF;
  float* const Mmem = ws + W_MEM;
  float* const part = ws + W_PART;
  const float* const pre = ws + W_PRE;
  const float* const wwrT = ws + W_WWRT;
  const float* const woutT = ws + W_WOUTT;
  const float* const wcomb = ws + W_WCOMB;
  const float* const bcomb = ws + W_BCOMB;
  int* const barA = (int*)(ws + W_BARA);
  int* const barB = (int*)(ws + W_BARB);
  int* const arrC = (int*)(ws + W_ARRC);
  int* const flg = (int*)(ws + W_FLG);
  int* const garr = (int*)(ws + W_GARR);

  const int w = blockIdx.x;
  const int tid = threadIdx.x;
  const int q = w >> 6;  // quarter (row split of the 1536 sequential rows)
  const int g = w & 63;  // column group (16 s-values per group)
  const float4* const blk4 =
      (const float4*)(ws + W_WLRP + (size_t)w * (384 * 16 * 4));

  __shared__ float xs[384];
  __shared__ float pg[64];
  __shared__ float red[4][16][17];
  __shared__ float gsum[64];
  __shared__ float hlds[SS];
  __shared__ float t1[96], t2[96], s3[MM];
  __shared__ float lvold[MM], lnraw[MM], nvln_s[MM];
  __shared__ float m2s[160];
  __shared__ float wred[4];
  __shared__ float cred[3][4];

  for (int t = 0; t < TT; ++t) {
    // ---- wait for D(t-1), then phase A ----
    if (t > 0) {
      if (tid == 0) {
        const int* f = flg + (t - 1);
        while (ld_i(f) == 0) __builtin_amdgcn_s_sleep(1);
      }
      __syncthreads();
      // memory rank-1 update for step t-1 (same WG that reads this slice in C)
      if (w < 144) {
        int a = w / 3, ch = w % 3;
        float uda = ld_g(udv + a);
        float ivg = ld_g(invg);
        float* Mrow = Mmem + a * MSQ + ch * 768;
#pragma unroll
        for (int i = 0; i < 3; ++i) {
          int c = tid + i * 256;
          float kvv = ld_g(keyf + ch * 768 + c);
          Mrow[c] = Mrow[c] * ivg + uda * kvv;  // plain: WG-local data
        }
      }
    }
    // stage x = [err(512); h_prev(1024)] slice for this quarter
    {
      const float* hprev = hbuf + (((t & 1) ^ 1) * SS);
      for (int l = tid; l < 384; l += NTHR) {
        int ri = q * 384 + l;
        xs[l] = (ri < 512) ? ld_g(errv + ri) : ld_g(hprev + (ri - 512));
      }
      if (tid < 64)
        pg[tid] = pre[(size_t)t * NG + (tid >> 4) * 1024 + g * 16 + (tid & 15)];
    }
    __syncthreads();
    // matvec: this quarter's 384 rows x this group's 16 columns x 4 gate blocks
    // repacked layout: blk4[row*16 + jj] = {gate0,gate1,gate2,gate3}
    {
      int rl = tid >> 4, jj = tid & 15;
      float a0 = 0.f, a1 = 0.f, a2 = 0.f, a3 = 0.f;
#pragma unroll 4
      for (int it = 0; it < 24; ++it) {
        int l = rl + 16 * it;
        float4 v = blk4[l * 16 + jj];
        float xv = xs[l];
        a0 = fmaf(xv, v.x, a0);
        a1 = fmaf(xv, v.y, a1);
        a2 = fmaf(xv, v.z, a2);
        a3 = fmaf(xv, v.w, a3);
      }
      red[0][rl][jj] = a0; red[1][rl][jj] = a1;
      red[2][rl][jj] = a2; red[3][rl][jj] = a3;
    }
    __syncthreads();
    float psum = 0.f;
    if (tid < 64) {
      int gb = tid >> 4, jj2 = tid & 15;
#pragma unroll
      for (int rl = 0; rl < 16; ++rl) psum += red[gb][rl][jj2];
    }
    if (q != 0) {
      if (tid < 64) {
        int gb = tid >> 4, jj2 = tid & 15;
        st_g(part + (q - 1) * NG + gb * 1024 + g * 16 + jj2, psum);
      }
      __syncthreads();
      if (tid == 0)
        __hip_atomic_fetch_add(garr + g, 1, __ATOMIC_RELEASE, __HIP_MEMORY_SCOPE_AGENT);
    } else {
      // designated updater: wait for the other 3 quarters, finish gates + LSTM cell
      if (tid == 0) {
        int tgt = 3 * (t + 1);
        while (ld_i(garr + g) < tgt) __builtin_amdgcn_s_sleep(1);
      }
      __syncthreads();
      if (tid < 64) {
        int gb = tid >> 4, jj2 = tid & 15;
        float v = psum + pg[tid];
        v += ld_g(part + 0 * NG + gb * 1024 + g * 16 + jj2);
        v += ld_g(part + 1 * NG + gb * 1024 + g * 16 + jj2);
        v += ld_g(part + 2 * NG + gb * 1024 + g * 16 + jj2);
        gsum[tid] = v;
      }
      __syncthreads();
      if (tid < 16) {
        int s = g * 16 + tid;
        float gi = gsum[0 * 16 + tid], gg = gsum[1 * 16 + tid];
        float gf = gsum[2 * 16 + tid], go = gsum[3 * 16 + tid];
        float cn = sigm(gf + 1.f) * cv[s] + sigm(gi) * tanhf(gg);
        float hn = sigm(go) * tanhf(cn);
        cv[s] = cn;  // plain: always this WG
        st_g(hbuf + (t & 1) * SS + s, hn);
      }
    }
    fullbar(barA + t);

    // ---- phase B: 753 dots of h (write 145, read 96, h@W_out 512) ----
    {
      const float* hcur = hbuf + (t & 1) * SS;
      for (int l = tid; l < SS; l += NTHR) hlds[l] = ld_g(hcur + l);
    }
    __syncthreads();
    for (int d = w; d < NDOTS; d += NWG) {
      const float* wrow = (d < 241) ? (wwrT + (size_t)d * SS)
                                    : (woutT + (size_t)(d - 241) * SS);
      float acc = 0.f;
#pragma unroll
      for (int i = 0; i < 4; ++i)
        acc = fmaf(hlds[tid + i * 256], wrow[tid + i * 256], acc);
#pragma unroll
      for (int off = 32; off; off >>= 1) acc += __shfl_down(acc, off, 64);
      if ((tid & 63) == 0) wred[tid >> 6] = acc;
      __syncthreads();
      if (tid == 0) {
        float v = wred[0] + wred[1] + wred[2] + wred[3];
        if (d < 145) st_g(wrv + d, v + bwv[d]);
        else if (d < 241) st_g(wrv + d, v + brv[d - 145]);
        else st_g(hwo + (d - 241), v);
      }
      __syncthreads();
    }
    fullbar(barB + t);

    // ---- phase C: dual matvec over M + sum(M^2), per (row, chunk) unit ----
    if (w < 144) {
      int a = w / 3, ch = w % 3;
      if (tid < 96) t1[tid] = tanhf(ld_g(wrv + tid));                    // k1|k2
      else if (tid < 192) t2[tid - 96] = tanhf(ld_g(wrv + 145 + (tid - 96)));  // n|e
      __syncthreads();
      const float* Mrow = Mmem + a * MSQ + ch * 768;
      float sk = 0.f, sr = 0.f, s2 = 0.f;
#pragma unroll
      for (int i = 0; i < 3; ++i) {
        int c = tid + i * 256;
        int gc = ch * 768 + c;
        int a2 = gc / 48, b2 = gc - a2 * 48;
        float m = Mrow[c];
        sk = fmaf(m, t1[a2] * t1[48 + b2], sk);
        sr = fmaf(m, t2[a2] * t2[48 + b2], sr);
        s2 = fmaf(m, m, s2);
      }
#pragma unroll
      for (int off = 32; off; off >>= 1) {
        sk += __shfl_down(sk, off, 64);
        sr += __shfl_down(sr, off, 64);
        s2 += __shfl_down(s2, off, 64);
      }
      if ((tid & 63) == 0) {
        cred[0][tid >> 6] = sk; cred[1][tid >> 6] = sr; cred[2][tid >> 6] = s2;
      }
      __syncthreads();
      if (tid == 0) {
        st_g(voldp + a * 4 + ch, cred[0][0] + cred[0][1] + cred[0][2] + cred[0][3]);
        st_g(nrawp + a * 4 + ch, cred[1][0] + cred[1][1] + cred[1][2] + cred[1][3]);
        st_g(m2p + w, cred[2][0] + cred[2][1] + cred[2][2] + cred[2][3]);
      }
      __syncthreads();
      if (tid == 0)
        __hip_atomic_fetch_add(arrC + t, 1, __ATOMIC_RELEASE, __HIP_MEMORY_SCOPE_AGENT);
    }

    // ---- phase D (WG0 only): scalars, LN, output, error, update coeffs ----
    if (w == 0) {
      if (tid == 0) {
        while (ld_i(arrC + t) < 144) __builtin_amdgcn_s_sleep(1);
      }
      __syncthreads();
      // parallel staging: tanh heads, m2 partials, per-row partial sums
      if (tid < 96) t1[tid] = tanhf(ld_g(wrv + tid));
      else if (tid < 192) t2[tid - 96] = tanhf(ld_g(wrv + 145 + (tid - 96)));
      else if (tid < 240) s3[tid - 192] = tanhf(ld_g(wrv + 96 + (tid - 192)));  // v
      if (tid < 144) m2s[tid] = ld_g(m2p + tid);
      if (tid < MM) {
        lvold[tid] = ld_g(voldp + tid * 4) + ld_g(voldp + tid * 4 + 1) + ld_g(voldp + tid * 4 + 2);
        lnraw[tid] = ld_g(nrawp + tid * 4) + ld_g(nrawp + tid * 4 + 1) + ld_g(nrawp + tid * 4 + 2);
      }
      __syncthreads();
      if (tid < 64) {
        // wave 0 computes all scalars lane-parallel (a = lane, valid a<48)
        const int a = tid;
        const bool va = a < MM;
        float lv = 0.f, d = 0.f, t1a = 0.f, t1b = 0.f, t2a = 0.f, t2b = 0.f;
        float ln = 0.f, m2part = 0.f;
        if (va) {
          lv = lvold[a]; ln = lnraw[a];
          d = s3[a] - lv;
          t1a = t1[a]; t1b = t1[48 + a];
          t2a = t2[a]; t2b = t2[48 + a];
          m2part = m2s[a] + m2s[a + 48] + m2s[a + 96];
        }
        float beta = sigm(ld_g(wrv + 144));  // uniform across lanes
        float sdv = va ? d * lv : 0.f;
        float sdd = va ? d * d : 0.f;
        float sk1 = va ? t1a * t1a : 0.f;
        float sk2 = va ? t1b * t1b : 0.f;
        float skn = va ? t1a * t2a : 0.f;
        float ske = va ? t1b * t2b : 0.f;
#pragma unroll
        for (int off = 32; off; off >>= 1) {
          m2part += __shfl_down(m2part, off, 64);
          sdv += __shfl_down(sdv, off, 64);
          sdd += __shfl_down(sdd, off, 64);
          sk1 += __shfl_down(sk1, off, 64);
          sk2 += __shfl_down(sk2, off, 64);
          skn += __shfl_down(skn, off, 64);
          ske += __shfl_down(ske, off, 64);
        }
        float m2 = __shfl(m2part, 0, 64);
        sdv = __shfl(sdv, 0, 64);
        sdd = __shfl(sdd, 0, 64);
        sk1 = __shfl(sk1, 0, 64);
        sk2 = __shfl(sk2, 0, 64);
        skn = __shfl(skn, 0, 64);
        ske = __shfl(ske, 0, 64);
        float n2 = m2 + 2.f * beta * sdv + beta * beta * sdd * (sk1 * sk2);
        float gam = sqrtf(fmaxf(n2, 0.f));
        if (gam < 1.f) gam = 1.f;
        float ivg = 1.f / gam;
        float kdr = skn * ske;  // key . read_key
        float nv = va ? (ln + beta * d * kdr) * ivg : 0.f;
        float mean = nv, msq = nv * nv;
#pragma unroll
        for (int off = 32; off; off >>= 1) {
          mean += __shfl_down(mean, off, 64);
          msq += __shfl_down(msq, off, 64);
        }
        mean = __shfl(mean, 0, 64) * (1.f / 48.f);
        msq = __shfl(msq, 0, 64) * (1.f / 48.f);
        float rstd = rsqrtf(msq - mean * mean + 1e-5f);
        if (va) {
          nvln_s[a] = (nv - mean) * rstd;
          st_g(udv + a, beta * ivg * d);
        }
        if (tid == 0) st_g(invg, ivg);
      }
      __syncthreads();
      for (int i = tid; i < MSQ; i += NTHR) {
        int a2 = i / 48, b2 = i - a2 * 48;
        st_g(keyf + i, t1[a2] * t1[48 + b2]);
      }
      for (int o = tid; o < OO; o += NTHR) {
        float acc = ld_g(hwo + o) + bcomb[o];
#pragma unroll 8
        for (int a = 0; a < MM; ++a) acc = fmaf(nvln_s[a], wcomb[a * OO + o], acc);
        float y = 10.f * tanhf(acc * 0.1f);
        out[(size_t)t * OO + o] = y;
        st_g(errv + o, y - labels[(size_t)t * OO + o]);
      }
      __syncthreads();
      if (tid == 0)
        __hip_atomic_store(flg + t, 1, __ATOMIC_RELEASE, __HIP_MEMORY_SCOPE_AGENT);
    }
  }
}

extern "C" void kernel_launch(void* const* d_in, const int* in_sizes, int n_in,
                              void* d_out, int out_size, void* d_ws, size_t ws_size,
                              hipStream_t stream) {
  const float* inp = (const float*)d_in[0];
  const float* lab = (const float*)d_in[1];
  const float* Wl = (const float*)d_in[2];
  const float* bl = (const float*)d_in[3];
  const float* Ww = (const float*)d_in[4];
  const float* bw = (const float*)d_in[5];
  const float* Wr = (const float*)d_in[6];
  const float* br = (const float*)d_in[7];
  const float* Wrp = (const float*)d_in[8];
  const float* brp = (const float*)d_in[9];
  const float* Wo = (const float*)d_in[10];
  const float* bo = (const float*)d_in[11];
  float* ws = (float*)d_ws;
  float* outp = (float*)d_out;
  (void)in_sizes; (void)n_in; (void)out_size; (void)ws_size;

  hipMemsetAsync(d_ws, 0, (size_t)ZERO_WORDS * 4, stream);
  hipLaunchKernelGGL(build_wwrT, dim3((241 * SS + 255) / 256), dim3(256), 0, stream,
                     Ww, Wr, ws + W_WWRT);
  hipLaunchKernelGGL(build_woutT, dim3(OO * SS / 256), dim3(256), 0, stream,
                     Wo, ws + W_WOUTT);
  hipLaunchKernelGGL(repack_wl, dim3(1536 * NG / 256), dim3(256), 0, stream,
                     Wl, ws + W_WLRP);
  hipLaunchKernelGGL(wcomb_kernel, dim3(98), dim3(256), 0, stream,
                     Wrp, brp, Wo, bo, ws + W_WCOMB, ws + W_BCOMB);
  hipLaunchKernelGGL(pregate_gemm, dim3(64, 16), dim3(256), 0, stream,
                     inp, lab, Wl, bl, ws + W_PRE);
  hipLaunchKernelGGL(persistent_kernel, dim3(NWG), dim3(NTHR), 0, stream,
                     ws, lab, bw, br, outp);
}

// Round 6
// 37884.076 us; speedup vs baseline: 1.7839x; 1.3496x over previous
//
#include <hip/hip_runtime.h>
#include <math.h>

// FWMemory: T=1024 sequential ticks, persistent-kernel design.
// Phases per tick: A(gates matvec + LSTM) -> B(write/read/hWout dots) ->
// C(memory dual-matvec + ||M||^2) -> D(WG0: scalars, LN, out, err) -> A...
// R4: per-WG contiguous weight blocks -> L2-resident (FETCH 27MB->1.6MB/step).
// R5: phase D parallelized.
// R6: contention-free barriers. R5 still ~48us/step waiting; arithmetic says
// 256 serialized same-address fetch_adds (~150cy each w/ poller line-stealing)
// per barrier = ~40-55us/step. Split every arrive counter across distinct
// 4KB-apart cache lines (16-way for barA/barB, 9-way for arrC, 128B-stride
// garr), wave-0 multi-line poll + shuffle reduce, s_sleep backoff.

#define TT 1024
#define DD 2048
#define SS 1024
#define OO 512
#define MM 48
#define MSQ 2304
#define NG 4096
#define NWG 256
#define NTHR 256
#define NDOTS 753   // 241 head dots + 512 hWout dots

// ---- ws layout (4-byte word offsets) ----
#define W_FLG    0            // [1024] step-done flags
#define W_GARR   1024         // [64*32] per-column-group counters, 128B stride
#define W_BARA   3072         // [16*1024] barrier A: sub j at j*TT + t
#define W_BARB   19456        // [16*1024] barrier B
#define W_ARRC   35840        // [16*1024] phase-C arrivals (9 subs used)
#define W_HB     52224        // [2][1024] h double buffer
#define W_CV     54272        // [1024] c (WG-local)
#define W_ERR    55296        // [512]
#define W_WR     55808        // [256] raw write(145)+read(96) dots
#define W_HWO    56064        // [512] h @ W_out
#define W_VOLDP  56576        // [48*4] per-chunk partials of M@key
#define W_NRAWP  56832        // [48*4] per-chunk partials of M@rk
#define W_M2P    57088        // [160] per-unit partials of sum(M^2)
#define W_UD     57344        // [64]  beta*invg*delta[a]
#define W_INVG   57408        // [64]
#define W_KEYF   57472        // [2304] materialized key vector
#define W_MEM    59776        // [48*2304] fast-weight memory
#define W_PART   170368       // [3][4096] gate partials from quarters 1..3
#define ZERO_WORDS 182656
#define W_PRE    182656             // [1024*4096] precomputed gates
#define W_WWRT  (W_PRE + TT*NG)     // [241*1024] W_write|W_read transposed
#define W_WOUTT (W_WWRT + 241*SS)   // [512*1024] W_out transposed
#define W_WCOMB (W_WOUTT + OO*SS)   // [48*512]  W_rproj @ W_out
#define W_BCOMB (W_WCOMB + MM*OO)   // [512]     b_rproj @ W_out + b_out
#define W_WLRP  (W_BCOMB + OO)      // [256*384*16*4] repacked seq rows of W_lstm
#define WS_WORDS (W_WLRP + 1536*NG)

__device__ __forceinline__ float ld_g(const float* p) {
  return __hip_atomic_load(p, __ATOMIC_RELAXED, __HIP_MEMORY_SCOPE_AGENT);
}
__device__ __forceinline__ void st_g(float* p, float v) {
  __hip_atomic_store(p, v, __ATOMIC_RELAXED, __HIP_MEMORY_SCOPE_AGENT);
}
__device__ __forceinline__ int ld_i(const int* p) {
  return __hip_atomic_load(p, __ATOMIC_RELAXED, __HIP_MEMORY_SCOPE_AGENT);
}
__device__ __forceinline__ float sigm(float x) { return 1.f / (1.f + expf(-x)); }

// 16-way distributed grid barrier (one-shot per t). WG w adds to sub w&15
// (subs 4KB apart -> distinct MALL lines). Wave-0 lanes 0..15 poll all subs
// in one RT and shuffle-reduce.
__device__ __forceinline__ void fullbar2(int* base, int t) {
  __syncthreads();
  if (threadIdx.x == 0)
    __hip_atomic_fetch_add(base + (blockIdx.x & 15) * TT + t, 1,
                           __ATOMIC_RELEASE, __HIP_MEMORY_SCOPE_AGENT);
  if (threadIdx.x < 64) {
    int total;
    do {
      int v = (threadIdx.x < 16) ? ld_i(base + threadIdx.x * TT + t) : 0;
#pragma unroll
      for (int off = 8; off; off >>= 1) v += __shfl_down(v, off, 64);
      total = __shfl(v, 0, 64);
      if (total < NWG) __builtin_amdgcn_s_sleep(2);
    } while (total < NWG);
  }
  __syncthreads();
}

// ---------------- one-time prep kernels ----------------

__global__ void build_wwrT(const float* __restrict__ Ww, const float* __restrict__ Wr,
                           float* __restrict__ wwrT) {
  int id = blockIdx.x * 256 + threadIdx.x;
  if (id < 241 * SS) {
    int d = id >> 10, s = id & 1023;
    wwrT[id] = (d < 145) ? Ww[s * 145 + d] : Wr[s * 96 + (d - 145)];
  }
}

__global__ void build_woutT(const float* __restrict__ Wo, float* __restrict__ woutT) {
  int id = blockIdx.x * 256 + threadIdx.x;  // 512*1024 exact
  int o = id >> 10, s = id & 1023;
  woutT[id] = Wo[s * OO + o];
}

// Repack W_lstm sequential rows into per-WG contiguous blocks.
__global__ void repack_wl(const float* __restrict__ Wl, float* __restrict__ dst) {
  int id = blockIdx.x * 256 + threadIdx.x;
  int gb = id & 3;
  int jj = (id >> 2) & 15;
  int tmp = id >> 6;
  int row = tmp % 384;
  int w = tmp / 384;
  int q = w >> 6, g = w & 63;
  int ri = q * 384 + row;
  int wrow = (ri < 512) ? (2048 + ri) : (2560 + ri);
  dst[id] = Wl[(size_t)wrow * NG + gb * 1024 + g * 16 + jj];
}

__global__ void wcomb_kernel(const float* __restrict__ Wrp, const float* __restrict__ brp,
                             const float* __restrict__ Wo, const float* __restrict__ bo,
                             float* __restrict__ wcomb, float* __restrict__ bcomb) {
  int id = blockIdx.x * 256 + threadIdx.x;  // 49*512 exact
  int a = id >> 9, o = id & 511;
  if (a < MM) {
    float acc = 0.f;
    for (int s = 0; s < SS; ++s) acc = fmaf(Wrp[a * SS + s], Wo[s * OO + o], acc);
    wcomb[a * OO + o] = acc;
  } else if (a == MM) {
    float acc = bo[o];
    for (int s = 0; s < SS; ++s) acc = fmaf(brp[s], Wo[s * OO + o], acc);
    bcomb[o] = acc;
  }
}

// pregates[t][j] = b_lstm[j] + inp[t] @ Wl[0:2048] + labels[t-1] @ Wl[2560:3072]
__global__ __launch_bounds__(256)
void pregate_gemm(const float* __restrict__ inp, const float* __restrict__ lab,
                  const float* __restrict__ Wl, const float* __restrict__ bl,
                  float* __restrict__ pre) {
  __shared__ float As[16][65];
  __shared__ float Bs[16][64];
  const int tid = threadIdx.x;
  const int j0 = blockIdx.x * 64;
  const int t0 = blockIdx.y * 64;
  const int tx = tid & 15, ty = tid >> 4;
  float acc[4][4] = {};
  for (int kc = 0; kc < 2560; kc += 16) {
    __syncthreads();
#pragma unroll
    for (int p = 0; p < 4; ++p) {
      int id = tid + p * 256;
      int r = id >> 4, kk = id & 15;
      int t = t0 + r, k = kc + kk;
      float v;
      if (k < DD) v = inp[(size_t)t * DD + k];
      else v = (t > 0) ? lab[(size_t)(t - 1) * OO + (k - DD)] : 0.f;
      As[kk][r] = v;
      int kr = id >> 6, j = id & 63;
      int k2 = kc + kr;
      int wrow = (k2 < DD) ? k2 : (512 + k2);  // 2560+(k2-2048)
      Bs[kr][j] = Wl[(size_t)wrow * NG + j0 + j];
    }
    __syncthreads();
#pragma unroll
    for (int kk = 0; kk < 16; ++kk) {
      float av[4], bv[4];
#pragma unroll
      for (int i = 0; i < 4; ++i) av[i] = As[kk][ty * 4 + i];
#pragma unroll
      for (int i = 0; i < 4; ++i) bv[i] = Bs[kk][tx * 4 + i];
#pragma unroll
      for (int i = 0; i < 4; ++i)
#pragma unroll
        for (int jx = 0; jx < 4; ++jx) acc[i][jx] = fmaf(av[i], bv[jx], acc[i][jx]);
    }
  }
#pragma unroll
  for (int i = 0; i < 4; ++i) {
    int t = t0 + ty * 4 + i;
#pragma unroll
    for (int jx = 0; jx < 4; ++jx) {
      int j = j0 + tx * 4 + jx;
      pre[(size_t)t * NG + j] = acc[i][jx] + bl[j];
    }
  }
}

// ---------------- persistent scan kernel ----------------

__global__ __launch_bounds__(NTHR, 1)
void persistent_kernel(float* ws, const float* __restrict__ labels,
                       const float* __restrict__ bwv, const float* __restrict__ brv,
                       float* __restrict__ out) {
  float* const hbuf = ws + W_HB;
  float* const cv = ws + W_CV;
  float* const errv = ws + W_ERR;
  float* const wrv = ws + W_WR;
  float* const hwo = ws + W_HWO;
  float* const voldp = ws + W_VOLDP;
  float* const nrawp = ws + W_NRAWP;
  float* const m2p = ws + W_M2P;
  float* const udv = ws + W_UD;
  float* const invg = ws + W_INVG;
  float* const keyf = ws + W_KEYF;
  float* const Mmem = ws + W_MEM;
  float* const part = ws + W_PART;
  const float* const pre = ws + W_PRE;
  const float* const wwrT = ws + W_WWRT;
  const float* const woutT = ws + W_WOUTT;
  const float* const wcomb = ws + W_WCOMB;
  const float* const bcomb = ws + W_BCOMB;
  int* const barA = (int*)(ws + W_BARA);
  int* const barB = (int*)(ws + W_BARB);
  int* const arrC = (int*)(ws + W_ARRC);
  int* const flg = (int*)(ws + W_FLG);
  int* const garr = (int*)(ws + W_GARR);

  const int w = blockIdx.x;
  const int tid = threadIdx.x;
  const int q = w >> 6;  // quarter (row split of the 1536 sequential rows)
  const int g = w & 63;  // column group (16 s-values per group)
  const float4* const blk4 =
      (const float4*)(ws + W_WLRP + (size_t)w * (384 * 16 * 4));

  __shared__ float xs[384];
  __shared__ float pg[64];
  __shared__ float red[4][16][17];
  __shared__ float gsum[64];
  __shared__ float hlds[SS];
  __shared__ float t1[96], t2[96], s3[MM];
  __shared__ float lvold[MM], lnraw[MM], nvln_s[MM];
  __shared__ float m2s[160];
  __shared__ float wred[4];
  __shared__ float cred[3][4];

  for (int t = 0; t < TT; ++t) {
    // ---- wait for D(t-1), then phase A ----
    if (t > 0) {
      if (tid == 0) {
        const int* f = flg + (t - 1);
        while (ld_i(f) == 0) __builtin_amdgcn_s_sleep(2);
      }
      __syncthreads();
      // memory rank-1 update for step t-1 (same WG that reads this slice in C)
      if (w < 144) {
        int a = w / 3, ch = w % 3;
        float uda = ld_g(udv + a);
        float ivg = ld_g(invg);
        float* Mrow = Mmem + a * MSQ + ch * 768;
#pragma unroll
        for (int i = 0; i < 3; ++i) {
          int c = tid + i * 256;
          float kvv = ld_g(keyf + ch * 768 + c);
          Mrow[c] = Mrow[c] * ivg + uda * kvv;  // plain: WG-local data
        }
      }
    }
    // stage x = [err(512); h_prev(1024)] slice for this quarter
    {
      const float* hprev = hbuf + (((t & 1) ^ 1) * SS);
      for (int l = tid; l < 384; l += NTHR) {
        int ri = q * 384 + l;
        xs[l] = (ri < 512) ? ld_g(errv + ri) : ld_g(hprev + (ri - 512));
      }
      if (tid < 64)
        pg[tid] = pre[(size_t)t * NG + (tid >> 4) * 1024 + g * 16 + (tid & 15)];
    }
    __syncthreads();
    // matvec: this quarter's 384 rows x this group's 16 columns x 4 gate blocks
    {
      int rl = tid >> 4, jj = tid & 15;
      float a0 = 0.f, a1 = 0.f, a2 = 0.f, a3 = 0.f;
#pragma unroll 4
      for (int it = 0; it < 24; ++it) {
        int l = rl + 16 * it;
        float4 v = blk4[l * 16 + jj];
        float xv = xs[l];
        a0 = fmaf(xv, v.x, a0);
        a1 = fmaf(xv, v.y, a1);
        a2 = fmaf(xv, v.z, a2);
        a3 = fmaf(xv, v.w, a3);
      }
      red[0][rl][jj] = a0; red[1][rl][jj] = a1;
      red[2][rl][jj] = a2; red[3][rl][jj] = a3;
    }
    __syncthreads();
    float psum = 0.f;
    if (tid < 64) {
      int gb = tid >> 4, jj2 = tid & 15;
#pragma unroll
      for (int rl = 0; rl < 16; ++rl) psum += red[gb][rl][jj2];
    }
    if (q != 0) {
      if (tid < 64) {
        int gb = tid >> 4, jj2 = tid & 15;
        st_g(part + (q - 1) * NG + gb * 1024 + g * 16 + jj2, psum);
      }
      __syncthreads();
      if (tid == 0)
        __hip_atomic_fetch_add(garr + g * 32, 1, __ATOMIC_RELEASE, __HIP_MEMORY_SCOPE_AGENT);
    } else {
      // designated updater: wait for the other 3 quarters, finish gates + LSTM cell
      if (tid == 0) {
        int tgt = 3 * (t + 1);
        const int* gc = garr + g * 32;
        while (ld_i(gc) < tgt) __builtin_amdgcn_s_sleep(2);
      }
      __syncthreads();
      if (tid < 64) {
        int gb = tid >> 4, jj2 = tid & 15;
        float v = psum + pg[tid];
        v += ld_g(part + 0 * NG + gb * 1024 + g * 16 + jj2);
        v += ld_g(part + 1 * NG + gb * 1024 + g * 16 + jj2);
        v += ld_g(part + 2 * NG + gb * 1024 + g * 16 + jj2);
        gsum[tid] = v;
      }
      __syncthreads();
      if (tid < 16) {
        int s = g * 16 + tid;
        float gi = gsum[0 * 16 + tid], gg = gsum[1 * 16 + tid];
        float gf = gsum[2 * 16 + tid], go = gsum[3 * 16 + tid];
        float cn = sigm(gf + 1.f) * cv[s] + sigm(gi) * tanhf(gg);
        float hn = sigm(go) * tanhf(cn);
        cv[s] = cn;  // plain: always this WG
        st_g(hbuf + (t & 1) * SS + s, hn);
      }
    }
    fullbar2(barA, t);

    // ---- phase B: 753 dots of h (write 145, read 96, h@W_out 512) ----
    {
      const float* hcur = hbuf + (t & 1) * SS;
      for (int l = tid; l < SS; l += NTHR) hlds[l] = ld_g(hcur + l);
    }
    __syncthreads();
    for (int d = w; d < NDOTS; d += NWG) {
      const float* wrow = (d < 241) ? (wwrT + (size_t)d * SS)
                                    : (woutT + (size_t)(d - 241) * SS);
      float acc = 0.f;
#pragma unroll
      for (int i = 0; i < 4; ++i)
        acc = fmaf(hlds[tid + i * 256], wrow[tid + i * 256], acc);
#pragma unroll
      for (int off = 32; off; off >>= 1) acc += __shfl_down(acc, off, 64);
      if ((tid & 63) == 0) wred[tid >> 6] = acc;
      __syncthreads();
      if (tid == 0) {
        float v = wred[0] + wred[1] + wred[2] + wred[3];
        if (d < 145) st_g(wrv + d, v + bwv[d]);
        else if (d < 241) st_g(wrv + d, v + brv[d - 145]);
        else st_g(hwo + (d - 241), v);
      }
      __syncthreads();
    }
    fullbar2(barB, t);

    // ---- phase C: dual matvec over M + sum(M^2), per (row, chunk) unit ----
    if (w < 144) {
      int a = w / 3, ch = w % 3;
      if (tid < 96) t1[tid] = tanhf(ld_g(wrv + tid));                    // k1|k2
      else if (tid < 192) t2[tid - 96] = tanhf(ld_g(wrv + 145 + (tid - 96)));  // n|e
      __syncthreads();
      const float* Mrow = Mmem + a * MSQ + ch * 768;
      float sk = 0.f, sr = 0.f, s2 = 0.f;
#pragma unroll
      for (int i = 0; i < 3; ++i) {
        int c = tid + i * 256;
        int gc = ch * 768 + c;
        int a2 = gc / 48, b2 = gc - a2 * 48;
        float m = Mrow[c];
        sk = fmaf(m, t1[a2] * t1[48 + b2], sk);
        sr = fmaf(m, t2[a2] * t2[48 + b2], sr);
        s2 = fmaf(m, m, s2);
      }
#pragma unroll
      for (int off = 32; off; off >>= 1) {
        sk += __shfl_down(sk, off, 64);
        sr += __shfl_down(sr, off, 64);
        s2 += __shfl_down(s2, off, 64);
      }
      if ((tid & 63) == 0) {
        cred[0][tid >> 6] = sk; cred[1][tid >> 6] = sr; cred[2][tid >> 6] = s2;
      }
      __syncthreads();
      if (tid == 0) {
        st_g(voldp + a * 4 + ch, cred[0][0] + cred[0][1] + cred[0][2] + cred[0][3]);
        st_g(nrawp + a * 4 + ch, cred[1][0] + cred[1][1] + cred[1][2] + cred[1][3]);
        st_g(m2p + w, cred[2][0] + cred[2][1] + cred[2][2] + cred[2][3]);
      }
      __syncthreads();
      if (tid == 0)
        __hip_atomic_fetch_add(arrC + (w >> 4) * TT + t, 1,
                               __ATOMIC_RELEASE, __HIP_MEMORY_SCOPE_AGENT);
    }

    // ---- phase D (WG0 only): scalars, LN, output, error, update coeffs ----
    if (w == 0) {
      if (tid < 64) {
        int total;
        do {
          int v = (tid < 9) ? ld_i(arrC + tid * TT + t) : 0;
#pragma unroll
          for (int off = 8; off; off >>= 1) v += __shfl_down(v, off, 64);
          total = __shfl(v, 0, 64);
          if (total < 144) __builtin_amdgcn_s_sleep(2);
        } while (total < 144);
      }
      __syncthreads();
      // parallel staging: tanh heads, m2 partials, per-row partial sums
      if (tid < 96) t1[tid] = tanhf(ld_g(wrv + tid));
      else if (tid < 192) t2[tid - 96] = tanhf(ld_g(wrv + 145 + (tid - 96)));
      else if (tid < 240) s3[tid - 192] = tanhf(ld_g(wrv + 96 + (tid - 192)));  // v
      if (tid < 144) m2s[tid] = ld_g(m2p + tid);
      if (tid < MM) {
        lvold[tid] = ld_g(voldp + tid * 4) + ld_g(voldp + tid * 4 + 1) + ld_g(voldp + tid * 4 + 2);
        lnraw[tid] = ld_g(nrawp + tid * 4) + ld_g(nrawp + tid * 4 + 1) + ld_g(nrawp + tid * 4 + 2);
      }
      __syncthreads();
      if (tid < 64) {
        // wave 0 computes all scalars lane-parallel (a = lane, valid a<48)
        const int a = tid;
        const bool va = a < MM;
        float lv = 0.f, d = 0.f, t1a = 0.f, t1b = 0.f, t2a = 0.f, t2b = 0.f;
        float ln = 0.f, m2part = 0.f;
        if (va) {
          lv = lvold[a]; ln = lnraw[a];
          d = s3[a] - lv;
          t1a = t1[a]; t1b = t1[48 + a];
          t2a = t2[a]; t2b = t2[48 + a];
          m2part = m2s[a] + m2s[a + 48] + m2s[a + 96];
        }
        float beta = sigm(ld_g(wrv + 144));  // uniform across lanes
        float sdv = va ? d * lv : 0.f;
        float sdd = va ? d * d : 0.f;
        float sk1 = va ? t1a * t1a : 0.f;
        float sk2 = va ? t1b * t1b : 0.f;
        float skn = va ? t1a * t2a : 0.f;
        float ske = va ? t1b * t2b : 0.f;
#pragma unroll
        for (int off = 32; off; off >>= 1) {
          m2part += __shfl_down(m2part, off, 64);
          sdv += __shfl_down(sdv, off, 64);
          sdd += __shfl_down(sdd, off, 64);
          sk1 += __shfl_down(sk1, off, 64);
          sk2 += __shfl_down(sk2, off, 64);
          skn += __shfl_down(skn, off, 64);
          ske += __shfl_down(ske, off, 64);
        }
        float m2 = __shfl(m2part, 0, 64);
        sdv = __shfl(sdv, 0, 64);
        sdd = __shfl(sdd, 0, 64);
        sk1 = __shfl(sk1, 0, 64);
        sk2 = __shfl(sk2, 0, 64);
        skn = __shfl(skn, 0, 64);
        ske = __shfl(ske, 0, 64);
        float n2 = m2 + 2.f * beta * sdv + beta * beta * sdd * (sk1 * sk2);
        float gam = sqrtf(fmaxf(n2, 0.f));
        if (gam < 1.f) gam = 1.f;
        float ivg = 1.f / gam;
        float kdr = skn * ske;  // key . read_key
        float nv = va ? (ln + beta * d * kdr) * ivg : 0.f;
        float mean = nv, msq = nv * nv;
#pragma unroll
        for (int off = 32; off; off >>= 1) {
          mean += __shfl_down(mean, off, 64);
          msq += __shfl_down(msq, off, 64);
        }
        mean = __shfl(mean, 0, 64) * (1.f / 48.f);
        msq = __shfl(msq, 0, 64) * (1.f / 48.f);
        float rstd = rsqrtf(msq - mean * mean + 1e-5f);
        if (va) {
          nvln_s[a] = (nv - mean) * rstd;
          st_g(udv + a, beta * ivg * d);
        }
        if (tid == 0) st_g(invg, ivg);
      }
      __syncthreads();
      for (int i = tid; i < MSQ; i += NTHR) {
        int a2 = i / 48, b2 = i - a2 * 48;
        st_g(keyf + i, t1[a2] * t1[48 + b2]);
      }
      for (int o = tid; o < OO; o += NTHR) {
        float acc = ld_g(hwo + o) + bcomb[o];
#pragma unroll 8
        for (int a = 0; a < MM; ++a) acc = fmaf(nvln_s[a], wcomb[a * OO + o], acc);
        float y = 10.f * tanhf(acc * 0.1f);
        out[(size_t)t * OO + o] = y;
        st_g(errv + o, y - labels[(size_t)t * OO + o]);
      }
      __syncthreads();
      if (tid == 0)
        __hip_atomic_store(flg + t, 1, __ATOMIC_RELEASE, __HIP_MEMORY_SCOPE_AGENT);
    }
  }
}

extern "C" void kernel_launch(void* const* d_in, const int* in_sizes, int n_in,
                              void* d_out, int out_size, void* d_ws, size_t ws_size,
                              hipStream_t stream) {
  const float* inp = (const float*)d_in[0];
  const float* lab = (const float*)d_in[1];
  const float* Wl = (const float*)d_in[2];
  const float* bl = (const float*)d_in[3];
  const float* Ww = (const float*)d_in[4];
  const float* bw = (const float*)d_in[5];
  const float* Wr = (const float*)d_in[6];
  const float* br = (const float*)d_in[7];
  const float* Wrp = (const float*)d_in[8];
  const float* brp = (const float*)d_in[9];
  const float* Wo = (const float*)d_in[10];
  const float* bo = (const float*)d_in[11];
  float* ws = (float*)d_ws;
  float* outp = (float*)d_out;
  (void)in_sizes; (void)n_in; (void)out_size; (void)ws_size;

  hipMemsetAsync(d_ws, 0, (size_t)ZERO_WORDS * 4, stream);
  hipLaunchKernelGGL(build_wwrT, dim3((241 * SS + 255) / 256), dim3(256), 0, stream,
                     Ww, Wr, ws + W_WWRT);
  hipLaunchKernelGGL(build_woutT, dim3(OO * SS / 256), dim3(256), 0, stream,
                     Wo, ws + W_WOUTT);
  hipLaunchKernelGGL(repack_wl, dim3(1536 * NG / 256), dim3(256), 0, stream,
                     Wl, ws + W_WLRP);
  hipLaunchKernelGGL(wcomb_kernel, dim3(98), dim3(256), 0, stream,
                     Wrp, brp, Wo, bo, ws + W_WCOMB, ws + W_BCOMB);
  hipLaunchKernelGGL(pregate_gemm, dim3(64, 16), dim3(256), 0, stream,
                     inp, lab, Wl, bl, ws + W_PRE);
  hipLaunchKernelGGL(persistent_kernel, dim3(NWG), dim3(NTHR), 0, stream,
                     ws, lab, bw, br, outp);
}

// Round 7
// 30402.032 us; speedup vs baseline: 2.2229x; 1.2461x over previous
//
#include <hip/hip_runtime.h>
#include <math.h>

// FWMemory: T=1024 sequential ticks, persistent-kernel design.
// Phases per tick: A(gates matvec + LSTM) -> B(write/read/hWout dots) ->
// C(memory dual-matvec + ||M||^2) -> D(WG0: scalars, LN, out, err) -> A...
// R4: per-WG contiguous weight blocks -> L2-resident (FETCH 27MB->1.6MB/step).
// R5: phase D parallelized. R6: 16-way split arrive counters (51->38ms).
// R7: zero-shared-line-polling barriers. R6 still had 256 WGs spin-loading
// the same 16 lines (and one flg line) -> MALL bank queueing inflates every
// barrier RT. Now: two-level arrive (16 subs + root, no pollers at all),
// unique last-arriver broadcasts epoch to 256 per-WG mailboxes (128B apart),
// each WG spins only on its OWN line (1 poller/line). flg -> same mailboxes.

#define TT 1024
#define DD 2048
#define SS 1024
#define OO 512
#define MM 48
#define MSQ 2304
#define NG 4096
#define NWG 256
#define NTHR 256
#define NDOTS 753   // 241 head dots + 512 hWout dots

// ---- ws layout (4-byte word offsets) ----
#define W_GARR   0            // [64*32] per-column-group counters, 128B stride
#define W_BARA   2048         // [17*1024] barrier A: sub j at j*TT+t, root j=16
#define W_BARB   19456        // [17*1024] barrier B
#define W_ARRC   36864        // [16*1024] phase-C arrivals (9 subs used)
#define W_MBF    53248        // [256*32] step-done mailboxes (epoch t+1)
#define W_MBA    61440        // [256*32] barrier-A mailboxes
#define W_MBB    69632        // [256*32] barrier-B mailboxes
#define W_HB     77824        // [2][1024] h double buffer
#define W_CV     79872        // [1024] c (WG-local)
#define W_ERR    80896        // [512]
#define W_WR     81408        // [256] raw write(145)+read(96) dots
#define W_HWO    81664        // [512] h @ W_out
#define W_VOLDP  82176        // [48*4] per-chunk partials of M@key
#define W_NRAWP  82432        // [48*4] per-chunk partials of M@rk
#define W_M2P    82688        // [160,pad256] per-unit partials of sum(M^2)
#define W_UD     82944        // [64]  beta*invg*delta[a]
#define W_INVG   83008        // [64]
#define W_KEYF   83072        // [2304] materialized key vector  (ends 85376)
#define W_MEM    85376        // [48*2304] fast-weight memory (ends 195968)
#define W_PART   195968       // [3][4096] gate partials (ends 208256)
#define ZERO_WORDS 208256
#define W_PRE    208256             // [1024*4096] precomputed gates
#define W_WWRT  (W_PRE + TT*NG)     // [241*1024] W_write|W_read transposed
#define W_WOUTT (W_WWRT + 241*SS)   // [512*1024] W_out transposed
#define W_WCOMB (W_WOUTT + OO*SS)   // [48*512]  W_rproj @ W_out
#define W_BCOMB (W_WCOMB + MM*OO)   // [512]     b_rproj @ W_out + b_out
#define W_WLRP  (W_BCOMB + OO)      // [256*384*16*4] repacked seq rows of W_lstm
#define WS_WORDS (W_WLRP + 1536*NG)

__device__ __forceinline__ float ld_g(const float* p) {
  return __hip_atomic_load(p, __ATOMIC_RELAXED, __HIP_MEMORY_SCOPE_AGENT);
}
__device__ __forceinline__ void st_g(float* p, float v) {
  __hip_atomic_store(p, v, __ATOMIC_RELAXED, __HIP_MEMORY_SCOPE_AGENT);
}
__device__ __forceinline__ int ld_i(const int* p) {
  return __hip_atomic_load(p, __ATOMIC_RELAXED, __HIP_MEMORY_SCOPE_AGENT);
}
__device__ __forceinline__ void st_i(int* p, int v) {
  __hip_atomic_store(p, v, __ATOMIC_RELAXED, __HIP_MEMORY_SCOPE_AGENT);
}
__device__ __forceinline__ float sigm(float x) { return 1.f / (1.f + expf(-x)); }

// Two-level arrive + unique-last-arriver broadcast + per-WG mailbox spin.
// Subs 4KB apart, root separate line, mailboxes 128B apart: no line has
// more than 16 RMWs or more than 1 poller.
__device__ __forceinline__ void bar3(int* subs, int* mb, int t, int* shflag) {
  const int tid = threadIdx.x;
  const int w = blockIdx.x;
  __syncthreads();
  if (tid == 0) {
    int bc = 0;
    int old = __hip_atomic_fetch_add(subs + (w & 15) * TT + t, 1,
                                     __ATOMIC_RELEASE, __HIP_MEMORY_SCOPE_AGENT);
    if (old == 15) {
      int rold = __hip_atomic_fetch_add(subs + 16 * TT + t, 1,
                                        __ATOMIC_RELEASE, __HIP_MEMORY_SCOPE_AGENT);
      bc = (rold == 15);
    }
    *shflag = bc;
  }
  __syncthreads();
  if (*shflag) {
    if (tid < 64) {
#pragma unroll
      for (int k = 0; k < 4; ++k) st_i(mb + (tid * 4 + k) * 32, t + 1);
    }
  } else if (tid == 0) {
    const int* p = mb + w * 32;
    while (ld_i(p) < t + 1) __builtin_amdgcn_s_sleep(1);
  }
  __syncthreads();
}

// ---------------- one-time prep kernels ----------------

__global__ void build_wwrT(const float* __restrict__ Ww, const float* __restrict__ Wr,
                           float* __restrict__ wwrT) {
  int id = blockIdx.x * 256 + threadIdx.x;
  if (id < 241 * SS) {
    int d = id >> 10, s = id & 1023;
    wwrT[id] = (d < 145) ? Ww[s * 145 + d] : Wr[s * 96 + (d - 145)];
  }
}

__global__ void build_woutT(const float* __restrict__ Wo, float* __restrict__ woutT) {
  int id = blockIdx.x * 256 + threadIdx.x;  // 512*1024 exact
  int o = id >> 10, s = id & 1023;
  woutT[id] = Wo[s * OO + o];
}

// Repack W_lstm sequential rows into per-WG contiguous blocks.
__global__ void repack_wl(const float* __restrict__ Wl, float* __restrict__ dst) {
  int id = blockIdx.x * 256 + threadIdx.x;
  int gb = id & 3;
  int jj = (id >> 2) & 15;
  int tmp = id >> 6;
  int row = tmp % 384;
  int w = tmp / 384;
  int q = w >> 6, g = w & 63;
  int ri = q * 384 + row;
  int wrow = (ri < 512) ? (2048 + ri) : (2560 + ri);
  dst[id] = Wl[(size_t)wrow * NG + gb * 1024 + g * 16 + jj];
}

__global__ void wcomb_kernel(const float* __restrict__ Wrp, const float* __restrict__ brp,
                             const float* __restrict__ Wo, const float* __restrict__ bo,
                             float* __restrict__ wcomb, float* __restrict__ bcomb) {
  int id = blockIdx.x * 256 + threadIdx.x;  // 49*512 exact
  int a = id >> 9, o = id & 511;
  if (a < MM) {
    float acc = 0.f;
    for (int s = 0; s < SS; ++s) acc = fmaf(Wrp[a * SS + s], Wo[s * OO + o], acc);
    wcomb[a * OO + o] = acc;
  } else if (a == MM) {
    float acc = bo[o];
    for (int s = 0; s < SS; ++s) acc = fmaf(brp[s], Wo[s * OO + o], acc);
    bcomb[o] = acc;
  }
}

// pregates[t][j] = b_lstm[j] + inp[t] @ Wl[0:2048] + labels[t-1] @ Wl[2560:3072]
__global__ __launch_bounds__(256)
void pregate_gemm(const float* __restrict__ inp, const float* __restrict__ lab,
                  const float* __restrict__ Wl, const float* __restrict__ bl,
                  float* __restrict__ pre) {
  __shared__ float As[16][65];
  __shared__ float Bs[16][64];
  const int tid = threadIdx.x;
  const int j0 = blockIdx.x * 64;
  const int t0 = blockIdx.y * 64;
  const int tx = tid & 15, ty = tid >> 4;
  float acc[4][4] = {};
  for (int kc = 0; kc < 2560; kc += 16) {
    __syncthreads();
#pragma unroll
    for (int p = 0; p < 4; ++p) {
      int id = tid + p * 256;
      int r = id >> 4, kk = id & 15;
      int t = t0 + r, k = kc + kk;
      float v;
      if (k < DD) v = inp[(size_t)t * DD + k];
      else v = (t > 0) ? lab[(size_t)(t - 1) * OO + (k - DD)] : 0.f;
      As[kk][r] = v;
      int kr = id >> 6, j = id & 63;
      int k2 = kc + kr;
      int wrow = (k2 < DD) ? k2 : (512 + k2);  // 2560+(k2-2048)
      Bs[kr][j] = Wl[(size_t)wrow * NG + j0 + j];
    }
    __syncthreads();
#pragma unroll
    for (int kk = 0; kk < 16; ++kk) {
      float av[4], bv[4];
#pragma unroll
      for (int i = 0; i < 4; ++i) av[i] = As[kk][ty * 4 + i];
#pragma unroll
      for (int i = 0; i < 4; ++i) bv[i] = Bs[kk][tx * 4 + i];
#pragma unroll
      for (int i = 0; i < 4; ++i)
#pragma unroll
        for (int jx = 0; jx < 4; ++jx) acc[i][jx] = fmaf(av[i], bv[jx], acc[i][jx]);
    }
  }
#pragma unroll
  for (int i = 0; i < 4; ++i) {
    int t = t0 + ty * 4 + i;
#pragma unroll
    for (int jx = 0; jx < 4; ++jx) {
      int j = j0 + tx * 4 + jx;
      pre[(size_t)t * NG + j] = acc[i][jx] + bl[j];
    }
  }
}

// ---------------- persistent scan kernel ----------------

__global__ __launch_bounds__(NTHR, 1)
void persistent_kernel(float* ws, const float* __restrict__ labels,
                       const float* __restrict__ bwv, const float* __restrict__ brv,
                       float* __restrict__ out) {
  float* const hbuf = ws + W_HB;
  float* const cv = ws + W_CV;
  float* const errv = ws + W_ERR;
  float* const wrv = ws + W_WR;
  float* const hwo = ws + W_HWO;
  float* const voldp = ws + W_VOLDP;
  float* const nrawp = ws + W_NRAWP;
  float* const m2p = ws + W_M2P;
  float* const udv = ws + W_UD;
  float* const invg = ws + W_INVG;
  float* const keyf = ws + W_KEYF;
  float* const Mmem = ws + W_MEM;
  float* const part = ws + W_PART;
  const float* const pre = ws + W_PRE;
  const float* const wwrT = ws + W_WWRT;
  const float* const woutT = ws + W_WOUTT;
  const float* const wcomb = ws + W_WCOMB;
  const float* const bcomb = ws + W_BCOMB;
  int* const barA = (int*)(ws + W_BARA);
  int* const barB = (int*)(ws + W_BARB);
  int* const arrC = (int*)(ws + W_ARRC);
  int* const mbF = (int*)(ws + W_MBF);
  int* const mbA = (int*)(ws + W_MBA);
  int* const mbB = (int*)(ws + W_MBB);
  int* const garr = (int*)(ws + W_GARR);

  const int w = blockIdx.x;
  const int tid = threadIdx.x;
  const int q = w >> 6;  // quarter (row split of the 1536 sequential rows)
  const int g = w & 63;  // column group (16 s-values per group)
  const float4* const blk4 =
      (const float4*)(ws + W_WLRP + (size_t)w * (384 * 16 * 4));

  __shared__ float xs[384];
  __shared__ float pg[64];
  __shared__ float red[4][16][17];
  __shared__ float gsum[64];
  __shared__ float hlds[SS];
  __shared__ float t1[96], t2[96], s3[MM];
  __shared__ float lvold[MM], lnraw[MM], nvln_s[MM];
  __shared__ float m2s[160];
  __shared__ float wred[4];
  __shared__ float cred[3][4];
  __shared__ int shflag;

  for (int t = 0; t < TT; ++t) {
    // ---- wait for D(t-1) via own mailbox, then phase A ----
    if (t > 0) {
      if (tid == 0 && w != 0) {
        const int* p = mbF + w * 32;
        while (ld_i(p) < t) __builtin_amdgcn_s_sleep(1);
      }
      __syncthreads();
      // memory rank-1 update for step t-1 (same WG that reads this slice in C)
      if (w < 144) {
        int a = w / 3, ch = w % 3;
        float uda = ld_g(udv + a);
        float ivg = ld_g(invg);
        float* Mrow = Mmem + a * MSQ + ch * 768;
#pragma unroll
        for (int i = 0; i < 3; ++i) {
          int c = tid + i * 256;
          float kvv = ld_g(keyf + ch * 768 + c);
          Mrow[c] = Mrow[c] * ivg + uda * kvv;  // plain: WG-local data
        }
      }
    }
    // stage x = [err(512); h_prev(1024)] slice for this quarter
    {
      const float* hprev = hbuf + (((t & 1) ^ 1) * SS);
      for (int l = tid; l < 384; l += NTHR) {
        int ri = q * 384 + l;
        xs[l] = (ri < 512) ? ld_g(errv + ri) : ld_g(hprev + (ri - 512));
      }
      if (tid < 64)
        pg[tid] = pre[(size_t)t * NG + (tid >> 4) * 1024 + g * 16 + (tid & 15)];
    }
    __syncthreads();
    // matvec: this quarter's 384 rows x this group's 16 columns x 4 gate blocks
    {
      int rl = tid >> 4, jj = tid & 15;
      float a0 = 0.f, a1 = 0.f, a2 = 0.f, a3 = 0.f;
#pragma unroll 4
      for (int it = 0; it < 24; ++it) {
        int l = rl + 16 * it;
        float4 v = blk4[l * 16 + jj];
        float xv = xs[l];
        a0 = fmaf(xv, v.x, a0);
        a1 = fmaf(xv, v.y, a1);
        a2 = fmaf(xv, v.z, a2);
        a3 = fmaf(xv, v.w, a3);
      }
      red[0][rl][jj] = a0; red[1][rl][jj] = a1;
      red[2][rl][jj] = a2; red[3][rl][jj] = a3;
    }
    __syncthreads();
    float psum = 0.f;
    if (tid < 64) {
      int gb = tid >> 4, jj2 = tid & 15;
#pragma unroll
      for (int rl = 0; rl < 16; ++rl) psum += red[gb][rl][jj2];
    }
    if (q != 0) {
      if (tid < 64) {
        int gb = tid >> 4, jj2 = tid & 15;
        st_g(part + (q - 1) * NG + gb * 1024 + g * 16 + jj2, psum);
      }
      __syncthreads();
      if (tid == 0)
        __hip_atomic_fetch_add(garr + g * 32, 1, __ATOMIC_RELEASE, __HIP_MEMORY_SCOPE_AGENT);
    } else {
      // designated updater: wait for the other 3 quarters, finish gates + LSTM cell
      if (tid == 0) {
        int tgt = 3 * (t + 1);
        const int* gc = garr + g * 32;
        while (ld_i(gc) < tgt) __builtin_amdgcn_s_sleep(1);
      }
      __syncthreads();
      if (tid < 64) {
        int gb = tid >> 4, jj2 = tid & 15;
        float v = psum + pg[tid];
        v += ld_g(part + 0 * NG + gb * 1024 + g * 16 + jj2);
        v += ld_g(part + 1 * NG + gb * 1024 + g * 16 + jj2);
        v += ld_g(part + 2 * NG + gb * 1024 + g * 16 + jj2);
        gsum[tid] = v;
      }
      __syncthreads();
      if (tid < 16) {
        int s = g * 16 + tid;
        float gi = gsum[0 * 16 + tid], gg = gsum[1 * 16 + tid];
        float gf = gsum[2 * 16 + tid], go = gsum[3 * 16 + tid];
        float cn = sigm(gf + 1.f) * cv[s] + sigm(gi) * tanhf(gg);
        float hn = sigm(go) * tanhf(cn);
        cv[s] = cn;  // plain: always this WG
        st_g(hbuf + (t & 1) * SS + s, hn);
      }
    }
    bar3(barA, mbA, t, &shflag);

    // ---- phase B: 753 dots of h (write 145, read 96, h@W_out 512) ----
    {
      const float* hcur = hbuf + (t & 1) * SS;
      for (int l = tid; l < SS; l += NTHR) hlds[l] = ld_g(hcur + l);
    }
    __syncthreads();
    for (int d = w; d < NDOTS; d += NWG) {
      const float* wrow = (d < 241) ? (wwrT + (size_t)d * SS)
                                    : (woutT + (size_t)(d - 241) * SS);
      float acc = 0.f;
#pragma unroll
      for (int i = 0; i < 4; ++i)
        acc = fmaf(hlds[tid + i * 256], wrow[tid + i * 256], acc);
#pragma unroll
      for (int off = 32; off; off >>= 1) acc += __shfl_down(acc, off, 64);
      if ((tid & 63) == 0) wred[tid >> 6] = acc;
      __syncthreads();
      if (tid == 0) {
        float v = wred[0] + wred[1] + wred[2] + wred[3];
        if (d < 145) st_g(wrv + d, v + bwv[d]);
        else if (d < 241) st_g(wrv + d, v + brv[d - 145]);
        else st_g(hwo + (d - 241), v);
      }
      __syncthreads();
    }
    bar3(barB, mbB, t, &shflag);

    // ---- phase C: dual matvec over M + sum(M^2), per (row, chunk) unit ----
    if (w < 144) {
      int a = w / 3, ch = w % 3;
      if (tid < 96) t1[tid] = tanhf(ld_g(wrv + tid));                    // k1|k2
      else if (tid < 192) t2[tid - 96] = tanhf(ld_g(wrv + 145 + (tid - 96)));  // n|e
      __syncthreads();
      const float* Mrow = Mmem + a * MSQ + ch * 768;
      float sk = 0.f, sr = 0.f, s2 = 0.f;
#pragma unroll
      for (int i = 0; i < 3; ++i) {
        int c = tid + i * 256;
        int gc = ch * 768 + c;
        int a2 = gc / 48, b2 = gc - a2 * 48;
        float m = Mrow[c];
        sk = fmaf(m, t1[a2] * t1[48 + b2], sk);
        sr = fmaf(m, t2[a2] * t2[48 + b2], sr);
        s2 = fmaf(m, m, s2);
      }
#pragma unroll
      for (int off = 32; off; off >>= 1) {
        sk += __shfl_down(sk, off, 64);
        sr += __shfl_down(sr, off, 64);
        s2 += __shfl_down(s2, off, 64);
      }
      if ((tid & 63) == 0) {
        cred[0][tid >> 6] = sk; cred[1][tid >> 6] = sr; cred[2][tid >> 6] = s2;
      }
      __syncthreads();
      if (tid == 0) {
        st_g(voldp + a * 4 + ch, cred[0][0] + cred[0][1] + cred[0][2] + cred[0][3]);
        st_g(nrawp + a * 4 + ch, cred[1][0] + cred[1][1] + cred[1][2] + cred[1][3]);
        st_g(m2p + w, cred[2][0] + cred[2][1] + cred[2][2] + cred[2][3]);
      }
      __syncthreads();
      if (tid == 0)
        __hip_atomic_fetch_add(arrC + (w >> 4) * TT + t, 1,
                               __ATOMIC_RELEASE, __HIP_MEMORY_SCOPE_AGENT);
    }

    // ---- phase D (WG0 only): scalars, LN, output, error, update coeffs ----
    if (w == 0) {
      if (tid < 64) {
        int total;
        do {
          int v = (tid < 9) ? ld_i(arrC + tid * TT + t) : 0;
#pragma unroll
          for (int off = 8; off; off >>= 1) v += __shfl_down(v, off, 64);
          total = __shfl(v, 0, 64);
          if (total < 144) __builtin_amdgcn_s_sleep(1);
        } while (total < 144);
      }
      __syncthreads();
      // parallel staging: tanh heads, m2 partials, per-row partial sums
      if (tid < 96) t1[tid] = tanhf(ld_g(wrv + tid));
      else if (tid < 192) t2[tid - 96] = tanhf(ld_g(wrv + 145 + (tid - 96)));
      else if (tid < 240) s3[tid - 192] = tanhf(ld_g(wrv + 96 + (tid - 192)));  // v
      if (tid < 144) m2s[tid] = ld_g(m2p + tid);
      if (tid < MM) {
        lvold[tid] = ld_g(voldp + tid * 4) + ld_g(voldp + tid * 4 + 1) + ld_g(voldp + tid * 4 + 2);
        lnraw[tid] = ld_g(nrawp + tid * 4) + ld_g(nrawp + tid * 4 + 1) + ld_g(nrawp + tid * 4 + 2);
      }
      __syncthreads();
      if (tid < 64) {
        // wave 0 computes all scalars lane-parallel (a = lane, valid a<48)
        const int a = tid;
        const bool va = a < MM;
        float lv = 0.f, d = 0.f, t1a = 0.f, t1b = 0.f, t2a = 0.f, t2b = 0.f;
        float ln = 0.f, m2part = 0.f;
        if (va) {
          lv = lvold[a]; ln = lnraw[a];
          d = s3[a] - lv;
          t1a = t1[a]; t1b = t1[48 + a];
          t2a = t2[a]; t2b = t2[48 + a];
          m2part = m2s[a] + m2s[a + 48] + m2s[a + 96];
        }
        float beta = sigm(ld_g(wrv + 144));  // uniform across lanes
        float sdv = va ? d * lv : 0.f;
        float sdd = va ? d * d : 0.f;
        float sk1 = va ? t1a * t1a : 0.f;
        float sk2 = va ? t1b * t1b : 0.f;
        float skn = va ? t1a * t2a : 0.f;
        float ske = va ? t1b * t2b : 0.f;
#pragma unroll
        for (int off = 32; off; off >>= 1) {
          m2part += __shfl_down(m2part, off, 64);
          sdv += __shfl_down(sdv, off, 64);
          sdd += __shfl_down(sdd, off, 64);
          sk1 += __shfl_down(sk1, off, 64);
          sk2 += __shfl_down(sk2, off, 64);
          skn += __shfl_down(skn, off, 64);
          ske += __shfl_down(ske, off, 64);
        }
        float m2 = __shfl(m2part, 0, 64);
        sdv = __shfl(sdv, 0, 64);
        sdd = __shfl(sdd, 0, 64);
        sk1 = __shfl(sk1, 0, 64);
        sk2 = __shfl(sk2, 0, 64);
        skn = __shfl(skn, 0, 64);
        ske = __shfl(ske, 0, 64);
        float n2 = m2 + 2.f * beta * sdv + beta * beta * sdd * (sk1 * sk2);
        float gam = sqrtf(fmaxf(n2, 0.f));
        if (gam < 1.f) gam = 1.f;
        float ivg = 1.f / gam;
        float kdr = skn * ske;  // key . read_key
        float nv = va ? (ln + beta * d * kdr) * ivg : 0.f;
        float mean = nv, msq = nv * nv;
#pragma unroll
        for (int off = 32; off; off >>= 1) {
          mean += __shfl_down(mean, off, 64);
          msq += __shfl_down(msq, off, 64);
        }
        mean = __shfl(mean, 0, 64) * (1.f / 48.f);
        msq = __shfl(msq, 0, 64) * (1.f / 48.f);
        float rstd = rsqrtf(msq - mean * mean + 1e-5f);
        if (va) {
          nvln_s[a] = (nv - mean) * rstd;
          st_g(udv + a, beta * ivg * d);
        }
        if (tid == 0) st_g(invg, ivg);
      }
      __syncthreads();
      for (int i = tid; i < MSQ; i += NTHR) {
        int a2 = i / 48, b2 = i - a2 * 48;
        st_g(keyf + i, t1[a2] * t1[48 + b2]);
      }
      for (int o = tid; o < OO; o += NTHR) {
        float acc = ld_g(hwo + o) + bcomb[o];
#pragma unroll 8
        for (int a = 0; a < MM; ++a) acc = fmaf(nvln_s[a], wcomb[a * OO + o], acc);
        float y = 10.f * tanhf(acc * 0.1f);
        out[(size_t)t * OO + o] = y;
        st_g(errv + o, y - labels[(size_t)t * OO + o]);
      }
      __syncthreads();
      // broadcast step-done epoch to all 256 per-WG mailboxes.
      // First store per lane is RELEASE (drains this wave's prior sc1 stores);
      // other waves' stores were drained by the preceding __syncthreads.
      if (tid < 64) {
        __hip_atomic_store(mbF + (tid * 4) * 32, t + 1,
                           __ATOMIC_RELEASE, __HIP_MEMORY_SCOPE_AGENT);
#pragma unroll
        for (int k = 1; k < 4; ++k)
          st_i(mbF + (tid * 4 + k) * 32, t + 1);
      }
    }
  }
}

extern "C" void kernel_launch(void* const* d_in, const int* in_sizes, int n_in,
                              void* d_out, int out_size, void* d_ws, size_t ws_size,
                              hipStream_t stream) {
  const float* inp = (const float*)d_in[0];
  const float* lab = (const float*)d_in[1];
  const float* Wl = (const float*)d_in[2];
  const float* bl = (const float*)d_in[3];
  const float* Ww = (const float*)d_in[4];
  const float* bw = (const float*)d_in[5];
  const float* Wr = (const float*)d_in[6];
  const float* br = (const float*)d_in[7];
  const float* Wrp = (const float*)d_in[8];
  const float* brp = (const float*)d_in[9];
  const float* Wo = (const float*)d_in[10];
  const float* bo = (const float*)d_in[11];
  float* ws = (float*)d_ws;
  float* outp = (float*)d_out;
  (void)in_sizes; (void)n_in; (void)out_size; (void)ws_size;

  hipMemsetAsync(d_ws, 0, (size_t)ZERO_WORDS * 4, stream);
  hipLaunchKernelGGL(build_wwrT, dim3((241 * SS + 255) / 256), dim3(256), 0, stream,
                     Ww, Wr, ws + W_WWRT);
  hipLaunchKernelGGL(build_woutT, dim3(OO * SS / 256), dim3(256), 0, stream,
                     Wo, ws + W_WOUTT);
  hipLaunchKernelGGL(repack_wl, dim3(1536 * NG / 256), dim3(256), 0, stream,
                     Wl, ws + W_WLRP);
  hipLaunchKernelGGL(wcomb_kernel, dim3(98), dim3(256), 0, stream,
                     Wrp, brp, Wo, bo, ws + W_WCOMB, ws + W_BCOMB);
  hipLaunchKernelGGL(pregate_gemm, dim3(64, 16), dim3(256), 0, stream,
                     inp, lab, Wl, bl, ws + W_PRE);
  hipLaunchKernelGGL(persistent_kernel, dim3(NWG), dim3(NTHR), 0, stream,
                     ws, lab, bw, br, outp);
}